// Round 19
// baseline (1071.749 us; speedup 1.0000x reference)
//
#include <hip/hip_runtime.h>
#include <cmath>

typedef float    f32x4 __attribute__((ext_vector_type(4)));
typedef _Float16 f16x8 __attribute__((ext_vector_type(8)));
typedef _Float16 f16x4 __attribute__((ext_vector_type(4)));

#define T_NUM 4096
#define H_DIM 1024
#define I_DIM 4096
#define MAXTILES 40
#define GEMMBLK 768
#define CWBLK 8192   // blocks per weight for coalesced convert (2^25 floats / 4096)

// ---- meta layout ----
#define M_COUNTS   0
#define M_CURSORS  48
#define M_OFFSETS  96
#define M_NTILES   144
#define M_TILE_E   152
#define M_TILE_M   392
#define M_TOPKI    1024
#define M_TOPKP    25600
#define M_STOK     50176
#define M_SPRB     74752

__device__ __forceinline__ float wave_sum(float v) {
  v += __shfl_xor(v, 32);
  v += __shfl_xor(v, 16);
  v += __shfl_xor(v, 8);
  v += __shfl_xor(v, 4);
  v += __shfl_xor(v, 2);
  v += __shfl_xor(v, 1);
  return v;
}

__device__ __forceinline__ void topk_write(int* meta, int layer, int t, const float* v) {
  int e0 = 0; float v0 = v[0];
  #pragma unroll
  for (int e = 1; e < 8; ++e) { if (v[e] > v0) { v0 = v[e]; e0 = e; } }
  int e1 = 0; float v1 = -3.4e38f;
  #pragma unroll
  for (int e = 0; e < 8; ++e) { if (e != e0 && v[e] > v1) { v1 = v[e]; e1 = e; } }
  float ex = expf(v1 - v0);
  float p0 = 1.f / (1.f + ex);
  float p1 = ex / (1.f + ex);
  meta[M_TOPKI + (layer * T_NUM + t) * 2    ] = e0;
  meta[M_TOPKI + (layer * T_NUM + t) * 2 + 1] = e1;
  ((float*)meta)[M_TOPKP + (layer * T_NUM + t) * 2    ] = p0;
  ((float*)meta)[M_TOPKP + (layer * T_NUM + t) * 2 + 1] = p1;
}

__global__ __launch_bounds__(256) void router_gu(const float* __restrict__ x,
    const float* __restrict__ Rg, const float* __restrict__ Ru, int* __restrict__ meta)
{
  int w = threadIdx.x >> 6, lane = threadIdx.x & 63;
  int t = blockIdx.x * 4 + w;
  const float* xr = x + (size_t)t * H_DIM + lane * 4;
  f32x4 xv[4];
  #pragma unroll
  for (int c = 0; c < 4; ++c) xv[c] = *(const f32x4*)(xr + c * 256);
  float lg[8], lu[8];
  #pragma unroll
  for (int e = 0; e < 8; ++e) {
    const float* rg = Rg + (size_t)e * H_DIM + lane * 4;
    const float* ru = Ru + (size_t)e * H_DIM + lane * 4;
    float sg = 0.f, su = 0.f;
    #pragma unroll
    for (int c = 0; c < 4; ++c) {
      f32x4 a = *(const f32x4*)(rg + c * 256);
      f32x4 b = *(const f32x4*)(ru + c * 256);
      sg += a[0]*xv[c][0] + a[1]*xv[c][1] + a[2]*xv[c][2] + a[3]*xv[c][3];
      su += b[0]*xv[c][0] + b[1]*xv[c][1] + b[2]*xv[c][2] + b[3]*xv[c][3];
    }
    lg[e] = wave_sum(sg);
    lu[e] = wave_sum(su);
  }
  if (lane == 0) {
    topk_write(meta, 0, t, lg);
    topk_write(meta, 1, t, lu);
  }
}

__global__ __launch_bounds__(256) void route_finalize(int* __restrict__ meta, int l0, int nl) {
  __shared__ int cnt_s[32];
  __shared__ int off_s[32];
  __shared__ int cur_s[32];
  int tid = threadIdx.x;
  if (tid < 32) { cnt_s[tid] = 0; cur_s[tid] = 0; }
  __syncthreads();
  for (int t = tid; t < T_NUM; t += 256) {
    for (int l = l0; l < l0 + nl; ++l) {
      int li = l - l0;
      #pragma unroll
      for (int k = 0; k < 2; ++k) {
        int e = meta[M_TOPKI + (l * T_NUM + t) * 2 + k];
        atomicAdd(&cnt_s[li * 16 + k * 8 + e], 1);
      }
    }
  }
  __syncthreads();
  if (tid == 0) {
    for (int l = l0; l < l0 + nl; ++l) {
      int li = l - l0;
      int off = 0;
      for (int k = 0; k < 2; ++k) {
        int nt = 0;
        for (int e = 0; e < 8; ++e) {
          int s = (l * 2 + k) * 8 + e;
          int c = cnt_s[li * 16 + k * 8 + e];
          meta[M_COUNTS + s] = c;
          meta[M_OFFSETS + s] = off;
          off_s[li * 16 + k * 8 + e] = off;
          for (int m = 0; m < c; m += 128) {
            meta[M_TILE_E + (l * 2 + k) * MAXTILES + nt] = e;
            meta[M_TILE_M + (l * 2 + k) * MAXTILES + nt] = m;
            ++nt;
          }
          off += c;
        }
        meta[M_NTILES + l * 2 + k] = nt;
      }
    }
  }
  __syncthreads();
  for (int t = tid; t < T_NUM; t += 256) {
    for (int l = l0; l < l0 + nl; ++l) {
      int li = l - l0;
      #pragma unroll
      for (int k = 0; k < 2; ++k) {
        int e = meta[M_TOPKI + (l * T_NUM + t) * 2 + k];
        float p = ((float*)meta)[M_TOPKP + (l * T_NUM + t) * 2 + k];
        int si = li * 16 + k * 8 + e;
        int pos = off_s[si] + atomicAdd(&cur_s[si], 1);
        meta[M_STOK + l * 8192 + pos] = t;
        ((float*)meta)[M_SPRB + l * 8192 + pos] = p;
      }
    }
  }
}

// ---- coalesced-read W convert (r19): thread = 16 CONSECUTIVE source floats;
// wave = one full 4KB row; output position derived (same layout as r2-r18:
// dst = c*4096 + fq*1024 + r*8). Writes are 16B scatters whose 64B sectors
// are completed by the block's 4 waves (rows 4r..4r+3) -> L2 merges.
template<int SPLITS, int NSH, int NB, int KSH, int KT>
__device__ __forceinline__ void convert_w2_body(const float* __restrict__ W,
    _Float16* __restrict__ Whi, _Float16* __restrict__ Wlo, int blk)
{
  size_t fi = ((size_t)blk * 256 + threadIdx.x) * 16;
  int row = (int)(fi >> KSH);
  int k   = (int)(fi & ((1 << KSH) - 1));
  int e   = row >> NSH;
  int nb  = (row >> 7) & (NB - 1);
  int r   = row & 127;
  int kt  = k >> 5;
  int fq  = (k >> 3) & 3;
  int c   = (e * NB + nb) * KT + kt;
  const float* src = W + fi;
  f32x4 v0 = *(const f32x4*)src;
  f32x4 v1 = *(const f32x4*)(src + 4);
  f32x4 v2 = *(const f32x4*)(src + 8);
  f32x4 v3 = *(const f32x4*)(src + 12);
  f16x8 h0, h1, l0, l1;
  #pragma unroll
  for (int q = 0; q < 8; ++q) {
    float a = (q < 4) ? v0[q] : v1[q - 4];
    float b = (q < 4) ? v2[q] : v3[q - 4];
    _Float16 ha = (_Float16)a, hb = (_Float16)b;
    h0[q] = ha; h1[q] = hb;
    if constexpr (SPLITS == 3) {
      l0[q] = (_Float16)(a - (float)ha);
      l1[q] = (_Float16)(b - (float)hb);
    }
  }
  size_t dst = (size_t)c * 4096 + fq * 1024 + r * 8;
  *(f16x8*)(Whi + dst)        = h0;
  *(f16x8*)(Whi + dst + 1024) = h1;   // second 8-group: fq+1, same kt (k%16==0)
  if constexpr (SPLITS == 3) {
    *(f16x8*)(Wlo + dst)        = l0;
    *(f16x8*)(Wlo + dst + 1024) = l1;
  }
}

__device__ __forceinline__ void gather_a_body(const float* __restrict__ X,
    _Float16* __restrict__ Apass, const int* __restrict__ meta, int layer, int kk, int gb)
{
  int pass = layer * 2 + kk;
  int tile = gb >> 5;
  int kt   = gb & 31;
  if (tile >= meta[M_NTILES + pass]) return;
  int m0   = meta[M_TILE_M + pass * MAXTILES + tile];
  int e    = meta[M_TILE_E + pass * MAXTILES + tile];
  int sidx = pass * 8 + e;
  int cnt  = meta[M_COUNTS + sidx];
  int seg  = meta[M_OFFSETS + sidx];
  const int* stok = meta + M_STOK + layer * 8192 + seg;
  size_t cb = ((size_t)tile * 32 + kt) * 8192;
  #pragma unroll
  for (int j = 0; j < 2; ++j) {
    int idx = threadIdx.x * 2 + j;
    int fq = idx >> 7, row = idx & 127;
    int m = m0 + row; if (m >= cnt) m = cnt - 1;
    const float* src = X + (size_t)stok[m] * H_DIM + kt * 32 + fq * 8;
    f32x4 v0 = *(const f32x4*)src;
    f32x4 v1 = *(const f32x4*)(src + 4);
    f16x8 h, l;
    #pragma unroll
    for (int q = 0; q < 8; ++q) {
      float v = (q < 4) ? v0[q] : v1[q - 4];
      _Float16 hv = (_Float16)v;
      h[q] = hv;
      l[q] = (_Float16)(v - (float)hv);
    }
    *(f16x8*)(Apass + cb + (size_t)idx * 8) = h;
    *(f16x8*)(Apass + cb + 4096 + (size_t)idx * 8) = l;
  }
}

__device__ __forceinline__ void gather_d_body(const _Float16* __restrict__ Gi,
    _Float16* __restrict__ Ad, const int* __restrict__ meta, int kk, int gb)
{
  int pass = 4 + kk;
  int tile = gb >> 7;
  int kt   = gb & 127;
  if (tile >= meta[M_NTILES + pass]) return;
  int m0   = meta[M_TILE_M + pass * MAXTILES + tile];
  int e    = meta[M_TILE_E + pass * MAXTILES + tile];
  int sidx = pass * 8 + e;
  int cnt  = meta[M_COUNTS + sidx];
  int seg  = meta[M_OFFSETS + sidx];
  const int* stok = meta + M_STOK + 2 * 8192 + seg;
  size_t cb = ((size_t)tile * 128 + kt) * 4096;
  #pragma unroll
  for (int j = 0; j < 2; ++j) {
    int idx = threadIdx.x * 2 + j;
    int fq = idx >> 7, row = idx & 127;
    int m = m0 + row; if (m >= cnt) m = cnt - 1;
    f16x8 h = *(const f16x8*)(Gi + (size_t)stok[m] * I_DIM + kt * 32 + fq * 8);
    *(f16x8*)(Ad + cb + (size_t)idx * 8) = h;
  }
}

// fusions (grids now use CWBLK per weight)
__global__ __launch_bounds__(256) void fused_cw3_ga(const float* __restrict__ W,
    _Float16* __restrict__ Whi, _Float16* __restrict__ Wlo,
    const float* __restrict__ X, _Float16* __restrict__ Atgt,
    const int* __restrict__ meta, int layer, int kk)
{
  int b = (int)blockIdx.x;
  if (b < CWBLK) convert_w2_body<3, 12, 32, 10, 32>(W, Whi, Wlo, b);
  else gather_a_body(X, Atgt, meta, layer, kk, b - CWBLK);
}

__global__ __launch_bounds__(256) void fused_cw3x2_ga(
    const float* __restrict__ Wg, _Float16* __restrict__ Wgh, _Float16* __restrict__ Wgl,
    const float* __restrict__ Wu, _Float16* __restrict__ Wuh, _Float16* __restrict__ Wul,
    const float* __restrict__ X, _Float16* __restrict__ Atgt, const int* __restrict__ meta)
{
  int b = (int)blockIdx.x;
  if (b < CWBLK) convert_w2_body<3, 12, 32, 10, 32>(Wg, Wgh, Wgl, b);
  else if (b < 2 * CWBLK) convert_w2_body<3, 12, 32, 10, 32>(Wu, Wuh, Wul, b - CWBLK);
  else gather_a_body(X, Atgt, meta, 0, 0, b - 2 * CWBLK);
}

__global__ __launch_bounds__(256) void fused_cw1_gd(const float* __restrict__ W,
    _Float16* __restrict__ Whi,
    const _Float16* __restrict__ Gi, _Float16* __restrict__ Adt,
    const int* __restrict__ meta, int kk)
{
  int b = (int)blockIdx.x;
  if (b < CWBLK) convert_w2_body<1, 10, 8, 12, 128>(W, Whi, Whi, b);
  else gather_d_body(Gi, Adt, meta, kk, b - CWBLK);
}

__global__ __launch_bounds__(256) void gather_a_k(const float* __restrict__ X,
    _Float16* __restrict__ Apass, const int* __restrict__ meta, int layer, int kk)
{
  gather_a_body(X, Apass, meta, layer, kk, (int)blockIdx.x);
}

__device__ __forceinline__ void gload16(const _Float16* g, _Float16* l) {
  __builtin_amdgcn_global_load_lds(
      (const __attribute__((address_space(1))) void*)g,
      (__attribute__((address_space(3))) void*)l, 16, 0, 0);
}

// Routed GEMM v9 + prologue work-stealing (r17-proven).
template<int SPLITS, int ADD, int N, int NB, int STEPS, int SPLITK, int STEAL>
__global__ __launch_bounds__(256, 3) void moe_gemm9(
    const _Float16* __restrict__ Aimg,
    const _Float16* __restrict__ Whi, const _Float16* __restrict__ Wlo,
    float* __restrict__ Out, float* __restrict__ Scr,
    const int* __restrict__ meta, int layer, int kk,
    const void* __restrict__ aux_src, _Float16* __restrict__ aux_dst,
    int alayer, int akk)
{
  constexpr int NWG = MAXTILES * NB * SPLITK;
  constexpr int Q8  = NWG / 8;
  constexpr int WCH = (SPLITS == 3) ? 1 : 2;
  constexpr int NPER = GEMMBLK / 8;

  __shared__ __align__(16) _Float16 sA[3 * 8192];

  if constexpr (STEAL == 1) {
    for (int gb = (int)blockIdx.x; gb < MAXTILES * 32; gb += GEMMBLK)
      gather_a_body((const float*)aux_src, aux_dst, meta, alayer, akk, gb);
  } else if constexpr (STEAL == 2) {
    for (int gb = (int)blockIdx.x; gb < MAXTILES * 128; gb += GEMMBLK)
      gather_d_body((const _Float16*)aux_src, aux_dst, meta, akk, gb);
  }

  int xcd  = (int)blockIdx.x & 7;
  int slot = (int)blockIdx.x >> 3;
  int pass = layer * 2 + kk;
  int ntiles = meta[M_NTILES + pass];

  int tid = threadIdx.x, lane = tid & 63, w = tid >> 6;
  int wr = w >> 1, wc = w & 1, fr = lane & 15, fq = lane >> 4;
  int aoff = (fq * 128 + wr * 64 + fr) * 8;

  for (int base = slot; base < Q8; base += NPER) {
    int logical = xcd * Q8 + base;
    int kc = 0, rem = logical;
    if constexpr (SPLITK == 2) { kc = logical / (MAXTILES * NB); rem = logical - kc * (MAXTILES * NB); }
    int tx = rem / NB;
    int ny = rem - tx * NB;
    if (tx >= ntiles) continue;

    int e    = meta[M_TILE_E + pass * MAXTILES + tx];
    int m0   = meta[M_TILE_M + pass * MAXTILES + tx];
    int sidx = pass * 8 + e;
    int cnt  = meta[M_COUNTS + sidx];
    int seg  = meta[M_OFFSETS + sidx];
    int n0   = ny * 128;

    const int*   stok = meta + M_STOK + layer * 8192 + seg;
    const float* sprb = (const float*)meta + M_SPRB + layer * 8192 + seg;

    const _Float16* At = Aimg + ((size_t)tx * SPLITK + kc) * STEPS * 8192;
    size_t wpanel = (size_t)(e * NB + ny) * (STEPS * WCH * SPLITK) * 4096;
    int kb = kc * STEPS * WCH;
    const _Float16* WhL = Whi + wpanel + (size_t)kb * 4096 + (fq * 128 + wc * 64 + fr) * 8;
    const _Float16* WlL = Wlo + wpanel + (size_t)kb * 4096 + (fq * 128 + wc * 64 + fr) * 8;

    auto stageA = [&](int it, int slot2) {
      const _Float16* s0 = At + (size_t)it * 8192 + w * 1024 + lane * 8;
      _Float16* d0 = sA + slot2 * 8192 + w * 1024;
      gload16(s0,        d0);
      gload16(s0 + 512,  d0 + 512);
      gload16(s0 + 4096, d0 + 4096);
      gload16(s0 + 4608, d0 + 4608);
    };
    auto loadW = [&](int it, f16x8 (&wh)[WCH][4], f16x8 (&wl)[1][4]) {
      #pragma unroll
      for (int c = 0; c < WCH; ++c) {
        size_t cb = (size_t)(it * WCH + c) * 4096;
        #pragma unroll
        for (int ni = 0; ni < 4; ++ni) wh[c][ni] = *(const f16x8*)(WhL + cb + ni * 128);
      }
      if constexpr (SPLITS == 3) {
        size_t cb = (size_t)it * 4096;
        #pragma unroll
        for (int ni = 0; ni < 4; ++ni) wl[0][ni] = *(const f16x8*)(WlL + cb + ni * 128);
      }
    };

    f32x4 acc[4][4];
    #pragma unroll
    for (int i = 0; i < 4; ++i)
      #pragma unroll
      for (int j = 0; j < 4; ++j) acc[i][j] = f32x4{0.f, 0.f, 0.f, 0.f};

    f16x8 w0h[WCH][4], w0l[1][4], w1h[WCH][4], w1l[1][4];
    int rc = 0, rs = 2;

    auto step = [&](int it, f16x8 (&cwh)[WCH][4], f16x8 (&cwl)[1][4],
                    f16x8 (&nwh)[WCH][4], f16x8 (&nwl)[1][4]) {
      int it2 = (it + 2 < STEPS) ? it + 2 : STEPS - 1;
      int it1 = (it + 1 < STEPS) ? it + 1 : STEPS - 1;
      stageA(it2, rs);
      loadW(it1, nwh, nwl);
      __builtin_amdgcn_sched_barrier(0);

      const _Float16* A0 = sA + rc * 8192;
      __builtin_amdgcn_s_setprio(1);
      if constexpr (SPLITS == 3) {
        f16x8 ah[4], al[4];
        #pragma unroll
        for (int mi = 0; mi < 4; ++mi) ah[mi] = *(const f16x8*)(A0 + aoff + mi * 128);
        #pragma unroll
        for (int mi = 0; mi < 4; ++mi) al[mi] = *(const f16x8*)(A0 + 4096 + aoff + mi * 128);
        #pragma unroll
        for (int mi = 0; mi < 4; ++mi)
          #pragma unroll
          for (int ni = 0; ni < 4; ++ni)
            acc[mi][ni] = __builtin_amdgcn_mfma_f32_16x16x32_f16(ah[mi], cwh[0][ni], acc[mi][ni], 0, 0, 0);
        #pragma unroll
        for (int mi = 0; mi < 4; ++mi)
          #pragma unroll
          for (int ni = 0; ni < 4; ++ni)
            acc[mi][ni] = __builtin_amdgcn_mfma_f32_16x16x32_f16(ah[mi], cwl[0][ni], acc[mi][ni], 0, 0, 0);
        #pragma unroll
        for (int mi = 0; mi < 4; ++mi)
          #pragma unroll
          for (int ni = 0; ni < 4; ++ni)
            acc[mi][ni] = __builtin_amdgcn_mfma_f32_16x16x32_f16(al[mi], cwh[0][ni], acc[mi][ni], 0, 0, 0);
      } else {
        #pragma unroll
        for (int c = 0; c < WCH; ++c) {
          f16x8 ah[4];
          #pragma unroll
          for (int mi = 0; mi < 4; ++mi) ah[mi] = *(const f16x8*)(A0 + c * 4096 + aoff + mi * 128);
          #pragma unroll
          for (int mi = 0; mi < 4; ++mi)
            #pragma unroll
            for (int ni = 0; ni < 4; ++ni)
              acc[mi][ni] = __builtin_amdgcn_mfma_f32_16x16x32_f16(ah[mi], cwh[c][ni], acc[mi][ni], 0, 0, 0);
        }
      }
      __builtin_amdgcn_s_setprio(0);

      __builtin_amdgcn_sched_barrier(0);
      asm volatile("s_waitcnt vmcnt(12)" ::: "memory");
      __builtin_amdgcn_s_barrier();
      __builtin_amdgcn_sched_barrier(0);
      rc = (rc == 2) ? 0 : rc + 1;
      rs = (rs == 2) ? 0 : rs + 1;
    };

    asm volatile("s_waitcnt vmcnt(0)" ::: "memory");
    __builtin_amdgcn_s_barrier();
    stageA(0, 0);
    stageA(1 < STEPS ? 1 : 0, 1);
    loadW(0, w0h, w0l);
    __builtin_amdgcn_sched_barrier(0);
    asm volatile("s_waitcnt vmcnt(12)" ::: "memory");
    __builtin_amdgcn_s_barrier();
    __builtin_amdgcn_sched_barrier(0);

    for (int it = 0; it < STEPS; it += 2) {
      step(it,     w0h, w0l, w1h, w1l);
      step(it + 1, w1h, w1l, w0h, w0l);
    }

    float* dst = (SPLITK == 2 && kc == 1) ? Scr : Out;
    #pragma unroll
    for (int mi = 0; mi < 4; ++mi) {
      #pragma unroll
      for (int jj = 0; jj < 4; ++jj) {
        int lm = wr * 64 + mi * 16 + fq * 4 + jj;
        int gm = m0 + lm;
        if (gm < cnt) {
          int tok = stok[gm];
          float p = sprb[gm];
          float* orow = dst + (size_t)tok * N + n0 + wc * 64 + fr;
          #pragma unroll
          for (int ni = 0; ni < 4; ++ni) {
            float v = p * acc[mi][ni][jj];
            if constexpr (ADD) orow[ni * 16] += v; else orow[ni * 16] = v;
          }
        }
      }
    }
  }
}

// fused SwiGLU + down-router; f16 inter out (r15-proven)
__global__ __launch_bounds__(256) void swiglu_router(const float* __restrict__ g,
    const float* __restrict__ u, const float* __restrict__ Rd,
    _Float16* __restrict__ gi, int* __restrict__ meta)
{
  int t = blockIdx.x, tid = threadIdx.x;
  float part[8];
  #pragma unroll
  for (int e = 0; e < 8; ++e) part[e] = 0.f;
  const float* gr = g + (size_t)t * I_DIM;
  const float* ur = u + (size_t)t * I_DIM;
  _Float16*    ir = gi + (size_t)t * I_DIM;
  #pragma unroll
  for (int cc = 0; cc < 4; ++cc) {
    int i = cc * 1024 + tid * 4;
    f32x4 gv = *(const f32x4*)(gr + i);
    f32x4 uv = *(const f32x4*)(ur + i);
    f32x4 iv;
    f16x4 hv;
    #pragma unroll
    for (int j = 0; j < 4; ++j) {
      float xx = gv[j];
      iv[j] = (xx / (1.f + expf(-xx))) * uv[j];
      hv[j] = (_Float16)iv[j];
    }
    *(f16x4*)(ir + i) = hv;
    #pragma unroll
    for (int e = 0; e < 8; ++e) {
      f32x4 rv = *(const f32x4*)(Rd + (size_t)e * I_DIM + i);
      part[e] += rv[0]*iv[0] + rv[1]*iv[1] + rv[2]*iv[2] + rv[3]*iv[3];
    }
  }
  __shared__ float red[4][8];
  int w = tid >> 6, lane = tid & 63;
  #pragma unroll
  for (int e = 0; e < 8; ++e) {
    float s = wave_sum(part[e]);
    if (lane == 0) red[w][e] = s;
  }
  __syncthreads();
  if (tid == 0) {
    float lg[8];
    #pragma unroll
    for (int e = 0; e < 8; ++e) lg[e] = red[0][e] + red[1][e] + red[2][e] + red[3][e];
    topk_write(meta, 2, t, lg);
  }
}

__global__ __launch_bounds__(256) void combine_kernel(float* __restrict__ out,
                                                      const float* __restrict__ scr)
{
  int i = blockIdx.x * 1024 + threadIdx.x * 4;
  f32x4 a = *(const f32x4*)(out + i);
  f32x4 b = *(const f32x4*)(scr + i);
  #pragma unroll
  for (int j = 0; j < 4; ++j) a[j] += b[j];
  *(f32x4*)(out + i) = a;
}

extern "C" void kernel_launch(void* const* d_in, const int* in_sizes, int n_in,
                              void* d_out, int out_size, void* d_ws, size_t ws_size,
                              hipStream_t stream)
{
  const float* x  = (const float*)d_in[0];
  const float* Rg = (const float*)d_in[1];
  const float* Wg = (const float*)d_in[2];
  const float* Ru = (const float*)d_in[3];
  const float* Wu = (const float*)d_in[4];
  const float* Rd = (const float*)d_in[5];
  const float* Wd = (const float*)d_in[6];
  float* out = (float*)d_out;
  char* ws = (char*)d_ws;

  const size_t MB64 = 67108864;
  const size_t A_SZ = 20971520;

  if (ws_size >= (size_t)445644800) {
    // ---- big-ws path (13 dispatches) ----
    _Float16* Wgh = (_Float16*)ws;
    _Float16* Wgl = (_Float16*)(ws + MB64);
    _Float16* Wuh = (_Float16*)(ws + 2 * MB64);
    _Float16* Wul = (_Float16*)(ws + 3 * MB64);
    float* g = (float*)(ws + 4 * MB64);
    float* u = (float*)(ws + 5 * MB64);
    int* meta = (int*)(ws + 6 * MB64);
    _Float16* A0 = (_Float16*)(ws + 6 * MB64 + 1048576);
    _Float16* A2 = (_Float16*)(ws + 6 * MB64 + 1048576 + A_SZ);
    _Float16* A1  = (_Float16*)u;
    _Float16* gi  = (_Float16*)Wgl;
    _Float16* Wdh = Wgh;
    _Float16* Ad0 = (_Float16*)u;
    _Float16* Ad1 = (_Float16*)g;
    float* dscr   = (float*)A0;

    router_gu<<<dim3(T_NUM / 4), 256, 0, stream>>>(x, Rg, Ru, meta);
    route_finalize<<<dim3(1), 256, 0, stream>>>(meta, 0, 2);

    fused_cw3x2_ga<<<dim3(2 * CWBLK + MAXTILES * 32), 256, 0, stream>>>(
        Wg, Wgh, Wgl, Wu, Wuh, Wul, x, A0, meta);
    moe_gemm9<3, 0, I_DIM, 32, 32, 1, 1><<<dim3(GEMMBLK), 256, 0, stream>>>(
        A0, Wgh, Wgl, g, g, meta, 0, 0, x, A1, 0, 1);
    moe_gemm9<3, 1, I_DIM, 32, 32, 1, 1><<<dim3(GEMMBLK), 256, 0, stream>>>(
        A1, Wgh, Wgl, g, g, meta, 0, 1, x, A0, 1, 0);
    moe_gemm9<3, 0, I_DIM, 32, 32, 1, 1><<<dim3(GEMMBLK), 256, 0, stream>>>(
        A0, Wuh, Wul, u, u, meta, 1, 0, x, A2, 1, 1);
    moe_gemm9<3, 1, I_DIM, 32, 32, 1, 0><<<dim3(GEMMBLK), 256, 0, stream>>>(
        A2, Wuh, Wul, u, u, meta, 1, 1, x, A2, 0, 0);

    swiglu_router<<<dim3(T_NUM), 256, 0, stream>>>(g, u, Rd, gi, meta);
    route_finalize<<<dim3(1), 256, 0, stream>>>(meta, 2, 1);

    fused_cw1_gd<<<dim3(CWBLK + MAXTILES * 128), 256, 0, stream>>>(Wd, Wdh, gi, Ad0, meta, 0);
    moe_gemm9<1, 0, H_DIM, 8, 32, 2, 2><<<dim3(GEMMBLK), 256, 0, stream>>>(
        Ad0, Wdh, Wdh, out, dscr, meta, 2, 0, gi, Ad1, 0, 1);
    moe_gemm9<1, 1, H_DIM, 8, 32, 2, 0><<<dim3(GEMMBLK), 256, 0, stream>>>(
        Ad1, Wdh, Wdh, out, dscr, meta, 2, 1, gi, Ad1, 0, 1);
    combine_kernel<<<dim3(T_NUM), 256, 0, stream>>>(out, dscr);
  } else {
    // ---- small-ws fallback (r17 sequence, new convert) ----
    _Float16* Wth = (_Float16*)ws;
    _Float16* Wtl = (_Float16*)(ws + MB64);
    float* g   = (float*)(ws + (size_t)134217728);
    float* u   = (float*)(ws + (size_t)201326592);
    int*  meta = (int*)(ws + (size_t)268435456);
    _Float16* A0 = (_Float16*)(ws + (size_t)269484032);
    _Float16* A1 = (_Float16*)u;
    _Float16* gi = (_Float16*)Wtl;
    _Float16* Ad0 = (_Float16*)u;
    _Float16* Ad1 = (_Float16*)g;
    float* dscr = (float*)A0;

    router_gu<<<dim3(T_NUM / 4), 256, 0, stream>>>(x, Rg, Ru, meta);
    route_finalize<<<dim3(1), 256, 0, stream>>>(meta, 0, 2);

    fused_cw3_ga<<<dim3(CWBLK + MAXTILES * 32), 256, 0, stream>>>(Wg, Wth, Wtl, x, A0, meta, 0, 0);
    moe_gemm9<3, 0, I_DIM, 32, 32, 1, 1><<<dim3(GEMMBLK), 256, 0, stream>>>(
        A0, Wth, Wtl, g, g, meta, 0, 0, x, A1, 0, 1);
    moe_gemm9<3, 1, I_DIM, 32, 32, 1, 1><<<dim3(GEMMBLK), 256, 0, stream>>>(
        A1, Wth, Wtl, g, g, meta, 0, 1, x, A0, 1, 0);
    fused_cw3_ga<<<dim3(CWBLK), 256, 0, stream>>>(Wu, Wth, Wtl, x, A0, meta, 0, 0);
    moe_gemm9<3, 0, I_DIM, 32, 32, 1, 0><<<dim3(GEMMBLK), 256, 0, stream>>>(
        A0, Wth, Wtl, u, u, meta, 1, 0, x, A0, 0, 0);
    gather_a_k<<<dim3(MAXTILES * 32), 256, 0, stream>>>(x, A0, meta, 1, 1);
    moe_gemm9<3, 1, I_DIM, 32, 32, 1, 0><<<dim3(GEMMBLK), 256, 0, stream>>>(
        A0, Wth, Wtl, u, u, meta, 1, 1, x, A0, 0, 0);

    swiglu_router<<<dim3(T_NUM), 256, 0, stream>>>(g, u, Rd, gi, meta);
    route_finalize<<<dim3(1), 256, 0, stream>>>(meta, 2, 1);

    fused_cw1_gd<<<dim3(CWBLK + MAXTILES * 128), 256, 0, stream>>>(Wd, Wth, gi, Ad0, meta, 0);
    moe_gemm9<1, 0, H_DIM, 8, 32, 2, 2><<<dim3(GEMMBLK), 256, 0, stream>>>(
        Ad0, Wth, Wth, out, dscr, meta, 2, 0, gi, Ad1, 0, 1);
    moe_gemm9<1, 1, H_DIM, 8, 32, 2, 0><<<dim3(GEMMBLK), 256, 0, stream>>>(
        Ad1, Wth, Wth, out, dscr, meta, 2, 1, gi, Ad1, 0, 1);
    combine_kernel<<<dim3(T_NUM), 256, 0, stream>>>(out, dscr);
  }
}

// Round 20
// 1034.951 us; speedup vs baseline: 1.0356x; 1.0356x over previous
//
#include <hip/hip_runtime.h>
#include <cmath>

typedef float    f32x4 __attribute__((ext_vector_type(4)));
typedef _Float16 f16x8 __attribute__((ext_vector_type(8)));
typedef _Float16 f16x4 __attribute__((ext_vector_type(4)));

#define T_NUM 4096
#define H_DIM 1024
#define I_DIM 4096
#define MAXTILES 40
#define GEMMBLK 768

// ---- meta layout ----
#define M_COUNTS   0
#define M_CURSORS  48
#define M_OFFSETS  96
#define M_NTILES   144
#define M_TILE_E   152
#define M_TILE_M   392
#define M_TOPKI    1024
#define M_TOPKP    25600
#define M_STOK     50176
#define M_SPRB     74752

__device__ __forceinline__ float wave_sum(float v) {
  v += __shfl_xor(v, 32);
  v += __shfl_xor(v, 16);
  v += __shfl_xor(v, 8);
  v += __shfl_xor(v, 4);
  v += __shfl_xor(v, 2);
  v += __shfl_xor(v, 1);
  return v;
}

__device__ __forceinline__ void topk_write(int* meta, int layer, int t, const float* v) {
  int e0 = 0; float v0 = v[0];
  #pragma unroll
  for (int e = 1; e < 8; ++e) { if (v[e] > v0) { v0 = v[e]; e0 = e; } }
  int e1 = 0; float v1 = -3.4e38f;
  #pragma unroll
  for (int e = 0; e < 8; ++e) { if (e != e0 && v[e] > v1) { v1 = v[e]; e1 = e; } }
  float ex = expf(v1 - v0);
  float p0 = 1.f / (1.f + ex);
  float p1 = ex / (1.f + ex);
  meta[M_TOPKI + (layer * T_NUM + t) * 2    ] = e0;
  meta[M_TOPKI + (layer * T_NUM + t) * 2 + 1] = e1;
  ((float*)meta)[M_TOPKP + (layer * T_NUM + t) * 2    ] = p0;
  ((float*)meta)[M_TOPKP + (layer * T_NUM + t) * 2 + 1] = p1;
}

__global__ __launch_bounds__(256) void router_gu(const float* __restrict__ x,
    const float* __restrict__ Rg, const float* __restrict__ Ru, int* __restrict__ meta)
{
  int w = threadIdx.x >> 6, lane = threadIdx.x & 63;
  int t = blockIdx.x * 4 + w;
  const float* xr = x + (size_t)t * H_DIM + lane * 4;
  f32x4 xv[4];
  #pragma unroll
  for (int c = 0; c < 4; ++c) xv[c] = *(const f32x4*)(xr + c * 256);
  float lg[8], lu[8];
  #pragma unroll
  for (int e = 0; e < 8; ++e) {
    const float* rg = Rg + (size_t)e * H_DIM + lane * 4;
    const float* ru = Ru + (size_t)e * H_DIM + lane * 4;
    float sg = 0.f, su = 0.f;
    #pragma unroll
    for (int c = 0; c < 4; ++c) {
      f32x4 a = *(const f32x4*)(rg + c * 256);
      f32x4 b = *(const f32x4*)(ru + c * 256);
      sg += a[0]*xv[c][0] + a[1]*xv[c][1] + a[2]*xv[c][2] + a[3]*xv[c][3];
      su += b[0]*xv[c][0] + b[1]*xv[c][1] + b[2]*xv[c][2] + b[3]*xv[c][3];
    }
    lg[e] = wave_sum(sg);
    lu[e] = wave_sum(su);
  }
  if (lane == 0) {
    topk_write(meta, 0, t, lg);
    topk_write(meta, 1, t, lu);
  }
}

__global__ __launch_bounds__(256) void route_finalize(int* __restrict__ meta, int l0, int nl) {
  __shared__ int cnt_s[32];
  __shared__ int off_s[32];
  __shared__ int cur_s[32];
  int tid = threadIdx.x;
  if (tid < 32) { cnt_s[tid] = 0; cur_s[tid] = 0; }
  __syncthreads();
  for (int t = tid; t < T_NUM; t += 256) {
    for (int l = l0; l < l0 + nl; ++l) {
      int li = l - l0;
      #pragma unroll
      for (int k = 0; k < 2; ++k) {
        int e = meta[M_TOPKI + (l * T_NUM + t) * 2 + k];
        atomicAdd(&cnt_s[li * 16 + k * 8 + e], 1);
      }
    }
  }
  __syncthreads();
  if (tid == 0) {
    for (int l = l0; l < l0 + nl; ++l) {
      int li = l - l0;
      int off = 0;
      for (int k = 0; k < 2; ++k) {
        int nt = 0;
        for (int e = 0; e < 8; ++e) {
          int s = (l * 2 + k) * 8 + e;
          int c = cnt_s[li * 16 + k * 8 + e];
          meta[M_COUNTS + s] = c;
          meta[M_OFFSETS + s] = off;
          off_s[li * 16 + k * 8 + e] = off;
          for (int m = 0; m < c; m += 128) {
            meta[M_TILE_E + (l * 2 + k) * MAXTILES + nt] = e;
            meta[M_TILE_M + (l * 2 + k) * MAXTILES + nt] = m;
            ++nt;
          }
          off += c;
        }
        meta[M_NTILES + l * 2 + k] = nt;
      }
    }
  }
  __syncthreads();
  for (int t = tid; t < T_NUM; t += 256) {
    for (int l = l0; l < l0 + nl; ++l) {
      int li = l - l0;
      #pragma unroll
      for (int k = 0; k < 2; ++k) {
        int e = meta[M_TOPKI + (l * T_NUM + t) * 2 + k];
        float p = ((float*)meta)[M_TOPKP + (l * T_NUM + t) * 2 + k];
        int si = li * 16 + k * 8 + e;
        int pos = off_s[si] + atomicAdd(&cur_s[si], 1);
        meta[M_STOK + l * 8192 + pos] = t;
        ((float*)meta)[M_SPRB + l * 8192 + pos] = p;
      }
    }
  }
}

// ---- shared device bodies (r18-verified: write-coalesced convert) ----
template<int SPLITS>
__device__ __forceinline__ void convert_w_body(const float* __restrict__ W,
    _Float16* __restrict__ Whi, _Float16* __restrict__ Wlo, int NB, int KT, int blk)
{
  size_t g = (size_t)blk * 256 + threadIdx.x;
  int c   = (int)(g >> 9);
  int rem = (int)(g & 511);
  int fq = rem >> 7, r = rem & 127;
  int e  = c / (NB * KT);
  int nb = (c / KT) % NB;
  int kt = c - (c / KT) * KT;
  int K = KT * 32, N = NB * 128;
  const float* src = W + ((size_t)(e * N + nb * 128 + r)) * K + kt * 32 + fq * 8;
  f32x4 v0 = *(const f32x4*)src;
  f32x4 v1 = *(const f32x4*)(src + 4);
  f16x8 h, l;
  #pragma unroll
  for (int q = 0; q < 8; ++q) {
    float v = (q < 4) ? v0[q] : v1[q - 4];
    _Float16 hv = (_Float16)v;
    h[q] = hv;
    l[q] = (_Float16)(v - (float)hv);
  }
  size_t dst = (size_t)c * 4096 + (size_t)rem * 8;
  *(f16x8*)(Whi + dst) = h;
  if constexpr (SPLITS == 3) *(f16x8*)(Wlo + dst) = l;
}

__device__ __forceinline__ void gather_a_body(const float* __restrict__ X,
    _Float16* __restrict__ Apass, const int* __restrict__ meta, int layer, int kk, int gb)
{
  int pass = layer * 2 + kk;
  int tile = gb >> 5;
  int kt   = gb & 31;
  if (tile >= meta[M_NTILES + pass]) return;
  int m0   = meta[M_TILE_M + pass * MAXTILES + tile];
  int e    = meta[M_TILE_E + pass * MAXTILES + tile];
  int sidx = pass * 8 + e;
  int cnt  = meta[M_COUNTS + sidx];
  int seg  = meta[M_OFFSETS + sidx];
  const int* stok = meta + M_STOK + layer * 8192 + seg;
  size_t cb = ((size_t)tile * 32 + kt) * 8192;
  #pragma unroll
  for (int j = 0; j < 2; ++j) {
    int idx = threadIdx.x * 2 + j;
    int fq = idx >> 7, row = idx & 127;
    int m = m0 + row; if (m >= cnt) m = cnt - 1;
    const float* src = X + (size_t)stok[m] * H_DIM + kt * 32 + fq * 8;
    f32x4 v0 = *(const f32x4*)src;
    f32x4 v1 = *(const f32x4*)(src + 4);
    f16x8 h, l;
    #pragma unroll
    for (int q = 0; q < 8; ++q) {
      float v = (q < 4) ? v0[q] : v1[q - 4];
      _Float16 hv = (_Float16)v;
      h[q] = hv;
      l[q] = (_Float16)(v - (float)hv);
    }
    *(f16x8*)(Apass + cb + (size_t)idx * 8) = h;
    *(f16x8*)(Apass + cb + 4096 + (size_t)idx * 8) = l;
  }
}

__device__ __forceinline__ void gather_d_body(const _Float16* __restrict__ Gi,
    _Float16* __restrict__ Ad, const int* __restrict__ meta, int kk, int gb)
{
  int pass = 4 + kk;
  int tile = gb >> 7;
  int kt   = gb & 127;
  if (tile >= meta[M_NTILES + pass]) return;
  int m0   = meta[M_TILE_M + pass * MAXTILES + tile];
  int e    = meta[M_TILE_E + pass * MAXTILES + tile];
  int sidx = pass * 8 + e;
  int cnt  = meta[M_COUNTS + sidx];
  int seg  = meta[M_OFFSETS + sidx];
  const int* stok = meta + M_STOK + 2 * 8192 + seg;
  size_t cb = ((size_t)tile * 128 + kt) * 4096;
  #pragma unroll
  for (int j = 0; j < 2; ++j) {
    int idx = threadIdx.x * 2 + j;
    int fq = idx >> 7, row = idx & 127;
    int m = m0 + row; if (m >= cnt) m = cnt - 1;
    f16x8 h = *(const f16x8*)(Gi + (size_t)stok[m] * I_DIM + kt * 32 + fq * 8);
    *(f16x8*)(Ad + cb + (size_t)idx * 8) = h;
  }
}

// parallel fusion (small-ws): convert Wg + gather_a
__global__ __launch_bounds__(256) void fused_cw3_ga(const float* __restrict__ W,
    _Float16* __restrict__ Whi, _Float16* __restrict__ Wlo,
    const float* __restrict__ X, _Float16* __restrict__ Atgt,
    const int* __restrict__ meta, int layer, int kk)
{
  int b = (int)blockIdx.x;
  if (b < 16384) convert_w_body<3>(W, Whi, Wlo, 32, 32, b);
  else gather_a_body(X, Atgt, meta, layer, kk, b - 16384);
}

// parallel fusion (big-ws): convert Wg + convert Wu + gather_a(0,0)
__global__ __launch_bounds__(256) void fused_cw3x2_ga(
    const float* __restrict__ Wg, _Float16* __restrict__ Wgh, _Float16* __restrict__ Wgl,
    const float* __restrict__ Wu, _Float16* __restrict__ Wuh, _Float16* __restrict__ Wul,
    const float* __restrict__ X, _Float16* __restrict__ Atgt, const int* __restrict__ meta)
{
  int b = (int)blockIdx.x;
  if (b < 16384) convert_w_body<3>(Wg, Wgh, Wgl, 32, 32, b);
  else if (b < 32768) convert_w_body<3>(Wu, Wuh, Wul, 32, 32, b - 16384);
  else gather_a_body(X, Atgt, meta, 0, 0, b - 32768);
}

__global__ __launch_bounds__(256) void fused_cw1_gd(const float* __restrict__ W,
    _Float16* __restrict__ Whi,
    const _Float16* __restrict__ Gi, _Float16* __restrict__ Adt,
    const int* __restrict__ meta, int kk)
{
  int b = (int)blockIdx.x;
  if (b < 16384) convert_w_body<1>(W, Whi, Whi, 8, 128, b);
  else gather_d_body(Gi, Adt, meta, kk, b - 16384);
}

__global__ __launch_bounds__(256) void gather_a_k(const float* __restrict__ X,
    _Float16* __restrict__ Apass, const int* __restrict__ meta, int layer, int kk)
{
  gather_a_body(X, Apass, meta, layer, kk, (int)blockIdx.x);
}

__device__ __forceinline__ void gload16(const _Float16* g, _Float16* l) {
  __builtin_amdgcn_global_load_lds(
      (const __attribute__((address_space(1))) void*)g,
      (__attribute__((address_space(3))) void*)l, 16, 0, 0);
}

// Routed GEMM v9 + prologue work-stealing (r17/r18-proven).
template<int SPLITS, int ADD, int N, int NB, int STEPS, int SPLITK, int STEAL>
__global__ __launch_bounds__(256, 3) void moe_gemm9(
    const _Float16* __restrict__ Aimg,
    const _Float16* __restrict__ Whi, const _Float16* __restrict__ Wlo,
    float* __restrict__ Out, float* __restrict__ Scr,
    const int* __restrict__ meta, int layer, int kk,
    const void* __restrict__ aux_src, _Float16* __restrict__ aux_dst,
    int alayer, int akk)
{
  constexpr int NWG = MAXTILES * NB * SPLITK;
  constexpr int Q8  = NWG / 8;
  constexpr int WCH = (SPLITS == 3) ? 1 : 2;
  constexpr int NPER = GEMMBLK / 8;

  __shared__ __align__(16) _Float16 sA[3 * 8192];

  if constexpr (STEAL == 1) {
    for (int gb = (int)blockIdx.x; gb < MAXTILES * 32; gb += GEMMBLK)
      gather_a_body((const float*)aux_src, aux_dst, meta, alayer, akk, gb);
  } else if constexpr (STEAL == 2) {
    for (int gb = (int)blockIdx.x; gb < MAXTILES * 128; gb += GEMMBLK)
      gather_d_body((const _Float16*)aux_src, aux_dst, meta, akk, gb);
  }

  int xcd  = (int)blockIdx.x & 7;
  int slot = (int)blockIdx.x >> 3;
  int pass = layer * 2 + kk;
  int ntiles = meta[M_NTILES + pass];

  int tid = threadIdx.x, lane = tid & 63, w = tid >> 6;
  int wr = w >> 1, wc = w & 1, fr = lane & 15, fq = lane >> 4;
  int aoff = (fq * 128 + wr * 64 + fr) * 8;

  for (int base = slot; base < Q8; base += NPER) {
    int logical = xcd * Q8 + base;
    int kc = 0, rem = logical;
    if constexpr (SPLITK == 2) { kc = logical / (MAXTILES * NB); rem = logical - kc * (MAXTILES * NB); }
    int tx = rem / NB;
    int ny = rem - tx * NB;
    if (tx >= ntiles) continue;

    int e    = meta[M_TILE_E + pass * MAXTILES + tx];
    int m0   = meta[M_TILE_M + pass * MAXTILES + tx];
    int sidx = pass * 8 + e;
    int cnt  = meta[M_COUNTS + sidx];
    int seg  = meta[M_OFFSETS + sidx];
    int n0   = ny * 128;

    const int*   stok = meta + M_STOK + layer * 8192 + seg;
    const float* sprb = (const float*)meta + M_SPRB + layer * 8192 + seg;

    const _Float16* At = Aimg + ((size_t)tx * SPLITK + kc) * STEPS * 8192;
    size_t wpanel = (size_t)(e * NB + ny) * (STEPS * WCH * SPLITK) * 4096;
    int kb = kc * STEPS * WCH;
    const _Float16* WhL = Whi + wpanel + (size_t)kb * 4096 + (fq * 128 + wc * 64 + fr) * 8;
    const _Float16* WlL = Wlo + wpanel + (size_t)kb * 4096 + (fq * 128 + wc * 64 + fr) * 8;

    auto stageA = [&](int it, int slot2) {
      const _Float16* s0 = At + (size_t)it * 8192 + w * 1024 + lane * 8;
      _Float16* d0 = sA + slot2 * 8192 + w * 1024;
      gload16(s0,        d0);
      gload16(s0 + 512,  d0 + 512);
      gload16(s0 + 4096, d0 + 4096);
      gload16(s0 + 4608, d0 + 4608);
    };
    auto loadW = [&](int it, f16x8 (&wh)[WCH][4], f16x8 (&wl)[1][4]) {
      #pragma unroll
      for (int c = 0; c < WCH; ++c) {
        size_t cb = (size_t)(it * WCH + c) * 4096;
        #pragma unroll
        for (int ni = 0; ni < 4; ++ni) wh[c][ni] = *(const f16x8*)(WhL + cb + ni * 128);
      }
      if constexpr (SPLITS == 3) {
        size_t cb = (size_t)it * 4096;
        #pragma unroll
        for (int ni = 0; ni < 4; ++ni) wl[0][ni] = *(const f16x8*)(WlL + cb + ni * 128);
      }
    };

    f32x4 acc[4][4];
    #pragma unroll
    for (int i = 0; i < 4; ++i)
      #pragma unroll
      for (int j = 0; j < 4; ++j) acc[i][j] = f32x4{0.f, 0.f, 0.f, 0.f};

    f16x8 w0h[WCH][4], w0l[1][4], w1h[WCH][4], w1l[1][4];
    int rc = 0, rs = 2;

    auto step = [&](int it, f16x8 (&cwh)[WCH][4], f16x8 (&cwl)[1][4],
                    f16x8 (&nwh)[WCH][4], f16x8 (&nwl)[1][4]) {
      int it2 = (it + 2 < STEPS) ? it + 2 : STEPS - 1;
      int it1 = (it + 1 < STEPS) ? it + 1 : STEPS - 1;
      stageA(it2, rs);
      loadW(it1, nwh, nwl);
      __builtin_amdgcn_sched_barrier(0);

      const _Float16* A0 = sA + rc * 8192;
      __builtin_amdgcn_s_setprio(1);
      if constexpr (SPLITS == 3) {
        f16x8 ah[4], al[4];
        #pragma unroll
        for (int mi = 0; mi < 4; ++mi) ah[mi] = *(const f16x8*)(A0 + aoff + mi * 128);
        #pragma unroll
        for (int mi = 0; mi < 4; ++mi) al[mi] = *(const f16x8*)(A0 + 4096 + aoff + mi * 128);
        #pragma unroll
        for (int mi = 0; mi < 4; ++mi)
          #pragma unroll
          for (int ni = 0; ni < 4; ++ni)
            acc[mi][ni] = __builtin_amdgcn_mfma_f32_16x16x32_f16(ah[mi], cwh[0][ni], acc[mi][ni], 0, 0, 0);
        #pragma unroll
        for (int mi = 0; mi < 4; ++mi)
          #pragma unroll
          for (int ni = 0; ni < 4; ++ni)
            acc[mi][ni] = __builtin_amdgcn_mfma_f32_16x16x32_f16(ah[mi], cwl[0][ni], acc[mi][ni], 0, 0, 0);
        #pragma unroll
        for (int mi = 0; mi < 4; ++mi)
          #pragma unroll
          for (int ni = 0; ni < 4; ++ni)
            acc[mi][ni] = __builtin_amdgcn_mfma_f32_16x16x32_f16(al[mi], cwh[0][ni], acc[mi][ni], 0, 0, 0);
      } else {
        #pragma unroll
        for (int c = 0; c < WCH; ++c) {
          f16x8 ah[4];
          #pragma unroll
          for (int mi = 0; mi < 4; ++mi) ah[mi] = *(const f16x8*)(A0 + c * 4096 + aoff + mi * 128);
          #pragma unroll
          for (int mi = 0; mi < 4; ++mi)
            #pragma unroll
            for (int ni = 0; ni < 4; ++ni)
              acc[mi][ni] = __builtin_amdgcn_mfma_f32_16x16x32_f16(ah[mi], cwh[c][ni], acc[mi][ni], 0, 0, 0);
        }
      }
      __builtin_amdgcn_s_setprio(0);

      __builtin_amdgcn_sched_barrier(0);
      asm volatile("s_waitcnt vmcnt(12)" ::: "memory");
      __builtin_amdgcn_s_barrier();
      __builtin_amdgcn_sched_barrier(0);
      rc = (rc == 2) ? 0 : rc + 1;
      rs = (rs == 2) ? 0 : rs + 1;
    };

    asm volatile("s_waitcnt vmcnt(0)" ::: "memory");
    __builtin_amdgcn_s_barrier();
    stageA(0, 0);
    stageA(1 < STEPS ? 1 : 0, 1);
    loadW(0, w0h, w0l);
    __builtin_amdgcn_sched_barrier(0);
    asm volatile("s_waitcnt vmcnt(12)" ::: "memory");
    __builtin_amdgcn_s_barrier();
    __builtin_amdgcn_sched_barrier(0);

    for (int it = 0; it < STEPS; it += 2) {
      step(it,     w0h, w0l, w1h, w1l);
      step(it + 1, w1h, w1l, w0h, w0l);
    }

    float* dst = (SPLITK == 2 && kc == 1) ? Scr : Out;
    #pragma unroll
    for (int mi = 0; mi < 4; ++mi) {
      #pragma unroll
      for (int jj = 0; jj < 4; ++jj) {
        int lm = wr * 64 + mi * 16 + fq * 4 + jj;
        int gm = m0 + lm;
        if (gm < cnt) {
          int tok = stok[gm];
          float p = sprb[gm];
          float* orow = dst + (size_t)tok * N + n0 + wc * 64 + fr;
          #pragma unroll
          for (int ni = 0; ni < 4; ++ni) {
            float v = p * acc[mi][ni][jj];
            if constexpr (ADD) orow[ni * 16] += v; else orow[ni * 16] = v;
          }
        }
      }
    }
  }
}

// fused SwiGLU + down-router; f16 inter out (r15-proven)
__global__ __launch_bounds__(256) void swiglu_router(const float* __restrict__ g,
    const float* __restrict__ u, const float* __restrict__ Rd,
    _Float16* __restrict__ gi, int* __restrict__ meta)
{
  int t = blockIdx.x, tid = threadIdx.x;
  float part[8];
  #pragma unroll
  for (int e = 0; e < 8; ++e) part[e] = 0.f;
  const float* gr = g + (size_t)t * I_DIM;
  const float* ur = u + (size_t)t * I_DIM;
  _Float16*    ir = gi + (size_t)t * I_DIM;
  #pragma unroll
  for (int cc = 0; cc < 4; ++cc) {
    int i = cc * 1024 + tid * 4;
    f32x4 gv = *(const f32x4*)(gr + i);
    f32x4 uv = *(const f32x4*)(ur + i);
    f32x4 iv;
    f16x4 hv;
    #pragma unroll
    for (int j = 0; j < 4; ++j) {
      float xx = gv[j];
      iv[j] = (xx / (1.f + expf(-xx))) * uv[j];
      hv[j] = (_Float16)iv[j];
    }
    *(f16x4*)(ir + i) = hv;
    #pragma unroll
    for (int e = 0; e < 8; ++e) {
      f32x4 rv = *(const f32x4*)(Rd + (size_t)e * I_DIM + i);
      part[e] += rv[0]*iv[0] + rv[1]*iv[1] + rv[2]*iv[2] + rv[3]*iv[3];
    }
  }
  __shared__ float red[4][8];
  int w = tid >> 6, lane = tid & 63;
  #pragma unroll
  for (int e = 0; e < 8; ++e) {
    float s = wave_sum(part[e]);
    if (lane == 0) red[w][e] = s;
  }
  __syncthreads();
  if (tid == 0) {
    float lg[8];
    #pragma unroll
    for (int e = 0; e < 8; ++e) lg[e] = red[0][e] + red[1][e] + red[2][e] + red[3][e];
    topk_write(meta, 2, t, lg);
  }
}

__global__ __launch_bounds__(256) void combine_kernel(float* __restrict__ out,
                                                      const float* __restrict__ scr)
{
  int i = blockIdx.x * 1024 + threadIdx.x * 4;
  f32x4 a = *(const f32x4*)(out + i);
  f32x4 b = *(const f32x4*)(scr + i);
  #pragma unroll
  for (int j = 0; j < 4; ++j) a[j] += b[j];
  *(f32x4*)(out + i) = a;
}

extern "C" void kernel_launch(void* const* d_in, const int* in_sizes, int n_in,
                              void* d_out, int out_size, void* d_ws, size_t ws_size,
                              hipStream_t stream)
{
  const float* x  = (const float*)d_in[0];
  const float* Rg = (const float*)d_in[1];
  const float* Wg = (const float*)d_in[2];
  const float* Ru = (const float*)d_in[3];
  const float* Wu = (const float*)d_in[4];
  const float* Rd = (const float*)d_in[5];
  const float* Wd = (const float*)d_in[6];
  float* out = (float*)d_out;
  char* ws = (char*)d_ws;

  const size_t MB64 = 67108864;
  const size_t A_SZ = 20971520;

  if (ws_size >= (size_t)445644800) {
    // ---- big-ws path: de-aliased W planes + third A image (13 dispatches) ----
    _Float16* Wgh = (_Float16*)ws;
    _Float16* Wgl = (_Float16*)(ws + MB64);
    _Float16* Wuh = (_Float16*)(ws + 2 * MB64);
    _Float16* Wul = (_Float16*)(ws + 3 * MB64);
    float* g = (float*)(ws + 4 * MB64);
    float* u = (float*)(ws + 5 * MB64);
    int* meta = (int*)(ws + 6 * MB64);
    _Float16* A0 = (_Float16*)(ws + 6 * MB64 + 1048576);
    _Float16* A2 = (_Float16*)(ws + 6 * MB64 + 1048576 + A_SZ);
    _Float16* A1  = (_Float16*)u;      // dead until gemm(1,0) writes u
    _Float16* gi  = (_Float16*)Wgl;    // Wg planes dead after layer-0 gemms
    _Float16* Wdh = Wgh;               // Wd f16 image in dead Wgh
    _Float16* Ad0 = (_Float16*)u;      // u dead after swiglu
    _Float16* Ad1 = (_Float16*)g;      // g dead after swiglu
    float* dscr   = (float*)A0;        // A0 dead in down phase

    router_gu<<<dim3(T_NUM / 4), 256, 0, stream>>>(x, Rg, Ru, meta);
    route_finalize<<<dim3(1), 256, 0, stream>>>(meta, 0, 2);

    fused_cw3x2_ga<<<dim3(32768 + MAXTILES * 32), 256, 0, stream>>>(
        Wg, Wgh, Wgl, Wu, Wuh, Wul, x, A0, meta);
    moe_gemm9<3, 0, I_DIM, 32, 32, 1, 1><<<dim3(GEMMBLK), 256, 0, stream>>>(
        A0, Wgh, Wgl, g, g, meta, 0, 0, x, A1, 0, 1);
    moe_gemm9<3, 1, I_DIM, 32, 32, 1, 1><<<dim3(GEMMBLK), 256, 0, stream>>>(
        A1, Wgh, Wgl, g, g, meta, 0, 1, x, A0, 1, 0);
    moe_gemm9<3, 0, I_DIM, 32, 32, 1, 1><<<dim3(GEMMBLK), 256, 0, stream>>>(
        A0, Wuh, Wul, u, u, meta, 1, 0, x, A2, 1, 1);
    moe_gemm9<3, 1, I_DIM, 32, 32, 1, 0><<<dim3(GEMMBLK), 256, 0, stream>>>(
        A2, Wuh, Wul, u, u, meta, 1, 1, x, A2, 0, 0);

    swiglu_router<<<dim3(T_NUM), 256, 0, stream>>>(g, u, Rd, gi, meta);
    route_finalize<<<dim3(1), 256, 0, stream>>>(meta, 2, 1);

    fused_cw1_gd<<<dim3(16384 + MAXTILES * 128), 256, 0, stream>>>(Wd, Wdh, gi, Ad0, meta, 0);
    moe_gemm9<1, 0, H_DIM, 8, 32, 2, 2><<<dim3(GEMMBLK), 256, 0, stream>>>(
        Ad0, Wdh, Wdh, out, dscr, meta, 2, 0, gi, Ad1, 0, 1);
    moe_gemm9<1, 1, H_DIM, 8, 32, 2, 0><<<dim3(GEMMBLK), 256, 0, stream>>>(
        Ad1, Wdh, Wdh, out, dscr, meta, 2, 1, gi, Ad1, 0, 1);
    combine_kernel<<<dim3(T_NUM), 256, 0, stream>>>(out, dscr);
  } else {
    // ---- small-ws fallback: r17 sequence ----
    _Float16* Wth = (_Float16*)ws;
    _Float16* Wtl = (_Float16*)(ws + MB64);
    float* g   = (float*)(ws + (size_t)134217728);
    float* u   = (float*)(ws + (size_t)201326592);
    int*  meta = (int*)(ws + (size_t)268435456);
    _Float16* A0 = (_Float16*)(ws + (size_t)269484032);
    _Float16* A1 = (_Float16*)u;
    _Float16* gi = (_Float16*)Wtl;
    _Float16* Ad0 = (_Float16*)u;
    _Float16* Ad1 = (_Float16*)g;
    float* dscr = (float*)A0;

    router_gu<<<dim3(T_NUM / 4), 256, 0, stream>>>(x, Rg, Ru, meta);
    route_finalize<<<dim3(1), 256, 0, stream>>>(meta, 0, 2);

    fused_cw3_ga<<<dim3(16384 + MAXTILES * 32), 256, 0, stream>>>(Wg, Wth, Wtl, x, A0, meta, 0, 0);
    moe_gemm9<3, 0, I_DIM, 32, 32, 1, 1><<<dim3(GEMMBLK), 256, 0, stream>>>(
        A0, Wth, Wtl, g, g, meta, 0, 0, x, A1, 0, 1);
    moe_gemm9<3, 1, I_DIM, 32, 32, 1, 1><<<dim3(GEMMBLK), 256, 0, stream>>>(
        A1, Wth, Wtl, g, g, meta, 0, 1, x, A0, 1, 0);
    fused_cw3_ga<<<dim3(16384), 256, 0, stream>>>(Wu, Wth, Wtl, x, A0, meta, 0, 0);
    moe_gemm9<3, 0, I_DIM, 32, 32, 1, 0><<<dim3(GEMMBLK), 256, 0, stream>>>(
        A0, Wth, Wtl, u, u, meta, 1, 0, x, A0, 0, 0);
    gather_a_k<<<dim3(MAXTILES * 32), 256, 0, stream>>>(x, A0, meta, 1, 1);
    moe_gemm9<3, 1, I_DIM, 32, 32, 1, 0><<<dim3(GEMMBLK), 256, 0, stream>>>(
        A0, Wth, Wtl, u, u, meta, 1, 1, x, A0, 0, 0);

    swiglu_router<<<dim3(T_NUM), 256, 0, stream>>>(g, u, Rd, gi, meta);
    route_finalize<<<dim3(1), 256, 0, stream>>>(meta, 2, 1);

    fused_cw1_gd<<<dim3(16384 + MAXTILES * 128), 256, 0, stream>>>(Wd, Wth, gi, Ad0, meta, 0);
    moe_gemm9<1, 0, H_DIM, 8, 32, 2, 2><<<dim3(GEMMBLK), 256, 0, stream>>>(
        Ad0, Wth, Wth, out, dscr, meta, 2, 0, gi, Ad1, 0, 1);
    moe_gemm9<1, 1, H_DIM, 8, 32, 2, 0><<<dim3(GEMMBLK), 256, 0, stream>>>(
        Ad1, Wth, Wth, out, dscr, meta, 2, 1, gi, Ad1, 0, 1);
    combine_kernel<<<dim3(T_NUM), 256, 0, stream>>>(out, dscr);
  }
}

// Round 21
// 935.744 us; speedup vs baseline: 1.1453x; 1.1060x over previous
//
#include <hip/hip_runtime.h>
#include <cmath>

typedef float    f32x4 __attribute__((ext_vector_type(4)));
typedef _Float16 f16x8 __attribute__((ext_vector_type(8)));
typedef _Float16 f16x4 __attribute__((ext_vector_type(4)));

#define T_NUM 4096
#define H_DIM 1024
#define I_DIM 4096
#define MAXTILES 40
#define GEMMBLK 768
#define CW3BLK 4096   // 8*32*16  (E*NB*KT/2) gate/up convert blocks
#define CW1BLK 4096   // 8*8*64   (E*NB*KT/2) down convert blocks

// ---- meta layout ----
#define M_COUNTS   0
#define M_CURSORS  48
#define M_OFFSETS  96
#define M_NTILES   144
#define M_TILE_E   152
#define M_TILE_M   392
#define M_TOPKI    1024
#define M_TOPKP    25600
#define M_STOK     50176
#define M_SPRB     74752

__device__ __forceinline__ float wave_sum(float v) {
  v += __shfl_xor(v, 32);
  v += __shfl_xor(v, 16);
  v += __shfl_xor(v, 8);
  v += __shfl_xor(v, 4);
  v += __shfl_xor(v, 2);
  v += __shfl_xor(v, 1);
  return v;
}

__device__ __forceinline__ void topk_write(int* meta, int layer, int t, const float* v) {
  int e0 = 0; float v0 = v[0];
  #pragma unroll
  for (int e = 1; e < 8; ++e) { if (v[e] > v0) { v0 = v[e]; e0 = e; } }
  int e1 = 0; float v1 = -3.4e38f;
  #pragma unroll
  for (int e = 0; e < 8; ++e) { if (e != e0 && v[e] > v1) { v1 = v[e]; e1 = e; } }
  float ex = expf(v1 - v0);
  float p0 = 1.f / (1.f + ex);
  float p1 = ex / (1.f + ex);
  meta[M_TOPKI + (layer * T_NUM + t) * 2    ] = e0;
  meta[M_TOPKI + (layer * T_NUM + t) * 2 + 1] = e1;
  ((float*)meta)[M_TOPKP + (layer * T_NUM + t) * 2    ] = p0;
  ((float*)meta)[M_TOPKP + (layer * T_NUM + t) * 2 + 1] = p1;
}

__global__ __launch_bounds__(256) void router_gu(const float* __restrict__ x,
    const float* __restrict__ Rg, const float* __restrict__ Ru, int* __restrict__ meta)
{
  int w = threadIdx.x >> 6, lane = threadIdx.x & 63;
  int t = blockIdx.x * 4 + w;
  const float* xr = x + (size_t)t * H_DIM + lane * 4;
  f32x4 xv[4];
  #pragma unroll
  for (int c = 0; c < 4; ++c) xv[c] = *(const f32x4*)(xr + c * 256);
  float lg[8], lu[8];
  #pragma unroll
  for (int e = 0; e < 8; ++e) {
    const float* rg = Rg + (size_t)e * H_DIM + lane * 4;
    const float* ru = Ru + (size_t)e * H_DIM + lane * 4;
    float sg = 0.f, su = 0.f;
    #pragma unroll
    for (int c = 0; c < 4; ++c) {
      f32x4 a = *(const f32x4*)(rg + c * 256);
      f32x4 b = *(const f32x4*)(ru + c * 256);
      sg += a[0]*xv[c][0] + a[1]*xv[c][1] + a[2]*xv[c][2] + a[3]*xv[c][3];
      su += b[0]*xv[c][0] + b[1]*xv[c][1] + b[2]*xv[c][2] + b[3]*xv[c][3];
    }
    lg[e] = wave_sum(sg);
    lu[e] = wave_sum(su);
  }
  if (lane == 0) {
    topk_write(meta, 0, t, lg);
    topk_write(meta, 1, t, lu);
  }
}

__global__ __launch_bounds__(256) void route_finalize(int* __restrict__ meta, int l0, int nl) {
  __shared__ int cnt_s[32];
  __shared__ int off_s[32];
  __shared__ int cur_s[32];
  int tid = threadIdx.x;
  if (tid < 32) { cnt_s[tid] = 0; cur_s[tid] = 0; }
  __syncthreads();
  for (int t = tid; t < T_NUM; t += 256) {
    for (int l = l0; l < l0 + nl; ++l) {
      int li = l - l0;
      #pragma unroll
      for (int k = 0; k < 2; ++k) {
        int e = meta[M_TOPKI + (l * T_NUM + t) * 2 + k];
        atomicAdd(&cnt_s[li * 16 + k * 8 + e], 1);
      }
    }
  }
  __syncthreads();
  if (tid == 0) {
    for (int l = l0; l < l0 + nl; ++l) {
      int li = l - l0;
      int off = 0;
      for (int k = 0; k < 2; ++k) {
        int nt = 0;
        for (int e = 0; e < 8; ++e) {
          int s = (l * 2 + k) * 8 + e;
          int c = cnt_s[li * 16 + k * 8 + e];
          meta[M_COUNTS + s] = c;
          meta[M_OFFSETS + s] = off;
          off_s[li * 16 + k * 8 + e] = off;
          for (int m = 0; m < c; m += 128) {
            meta[M_TILE_E + (l * 2 + k) * MAXTILES + nt] = e;
            meta[M_TILE_M + (l * 2 + k) * MAXTILES + nt] = m;
            ++nt;
          }
          off += c;
        }
        meta[M_NTILES + l * 2 + k] = nt;
      }
    }
  }
  __syncthreads();
  for (int t = tid; t < T_NUM; t += 256) {
    for (int l = l0; l < l0 + nl; ++l) {
      int li = l - l0;
      #pragma unroll
      for (int k = 0; k < 2; ++k) {
        int e = meta[M_TOPKI + (l * T_NUM + t) * 2 + k];
        float p = ((float*)meta)[M_TOPKP + (l * T_NUM + t) * 2 + k];
        int si = li * 16 + k * 8 + e;
        int pos = off_s[si] + atomicAdd(&cur_s[si], 1);
        meta[M_STOK + l * 8192 + pos] = t;
        ((float*)meta)[M_SPRB + l * 8192 + pos] = p;
      }
    }
  }
}

// ---- LDS-staged W convert (r21): coalesced reads (32 consecutive floats /
// thread, L1-merged lines), f16 split, LDS transpose to tiled layout,
// fully-coalesced 16B/lane linear stores. Output layout identical to
// r2-r20: element hi[c*4096 + fq*1024 + r*8 + q] = f16(W[row=panel*128+r]
// [kt*32 + fq*8 + q]), c = panel*KT + kt. Block = panel x 2-kt group.
template<int SPLITS, int NB, int KT>
__device__ __forceinline__ void convert_lds_body(const float* __restrict__ W,
    _Float16* __restrict__ Whi, _Float16* __restrict__ Wlo, int blk,
    _Float16* sHi, _Float16* sLo)
{
  constexpr int KTG = KT / 2;
  constexpr int K   = KT * 32;
  int panel = blk / KTG;          // e*NB + nb
  int ktg   = blk - panel * KTG;
  int t = threadIdx.x;
  int r = t >> 1, h = t & 1;

  const float* src = W + ((size_t)panel * 128 + r) * K + (ktg * 2 + h) * 32;
  f32x4 v[8];
  #pragma unroll
  for (int j = 0; j < 8; ++j) v[j] = *(const f32x4*)(src + j * 4);

  #pragma unroll
  for (int fq = 0; fq < 4; ++fq) {
    f16x8 hi8, lo8;
    #pragma unroll
    for (int q = 0; q < 8; ++q) {
      int idx = fq * 8 + q;
      float x = v[idx >> 2][idx & 3];
      _Float16 hx = (_Float16)x;
      hi8[q] = hx;
      if constexpr (SPLITS == 3) lo8[q] = (_Float16)(x - (float)hx);
    }
    int loff = h * 4096 + fq * 1024 + r * 8;
    *(f16x8*)(sHi + loff) = hi8;
    if constexpr (SPLITS == 3) *(f16x8*)(sLo + loff) = lo8;
  }
  __syncthreads();

  size_t base = ((size_t)panel * KT + ktg * 2) * 4096;   // 2 contiguous chunks
  #pragma unroll
  for (int j = 0; j < 4; ++j) {
    int o = (j * 256 + t) * 8;
    *(f16x8*)(Whi + base + o) = *(const f16x8*)(sHi + o);
  }
  if constexpr (SPLITS == 3) {
    #pragma unroll
    for (int j = 0; j < 4; ++j) {
      int o = (j * 256 + t) * 8;
      *(f16x8*)(Wlo + base + o) = *(const f16x8*)(sLo + o);
    }
  }
}

__device__ __forceinline__ void gather_a_body(const float* __restrict__ X,
    _Float16* __restrict__ Apass, const int* __restrict__ meta, int layer, int kk, int gb)
{
  int pass = layer * 2 + kk;
  int tile = gb >> 5;
  int kt   = gb & 31;
  if (tile >= meta[M_NTILES + pass]) return;
  int m0   = meta[M_TILE_M + pass * MAXTILES + tile];
  int e    = meta[M_TILE_E + pass * MAXTILES + tile];
  int sidx = pass * 8 + e;
  int cnt  = meta[M_COUNTS + sidx];
  int seg  = meta[M_OFFSETS + sidx];
  const int* stok = meta + M_STOK + layer * 8192 + seg;
  size_t cb = ((size_t)tile * 32 + kt) * 8192;
  #pragma unroll
  for (int j = 0; j < 2; ++j) {
    int idx = threadIdx.x * 2 + j;
    int fq = idx >> 7, row = idx & 127;
    int m = m0 + row; if (m >= cnt) m = cnt - 1;
    const float* src = X + (size_t)stok[m] * H_DIM + kt * 32 + fq * 8;
    f32x4 v0 = *(const f32x4*)src;
    f32x4 v1 = *(const f32x4*)(src + 4);
    f16x8 h, l;
    #pragma unroll
    for (int q = 0; q < 8; ++q) {
      float v = (q < 4) ? v0[q] : v1[q - 4];
      _Float16 hv = (_Float16)v;
      h[q] = hv;
      l[q] = (_Float16)(v - (float)hv);
    }
    *(f16x8*)(Apass + cb + (size_t)idx * 8) = h;
    *(f16x8*)(Apass + cb + 4096 + (size_t)idx * 8) = l;
  }
}

__device__ __forceinline__ void gather_d_body(const _Float16* __restrict__ Gi,
    _Float16* __restrict__ Ad, const int* __restrict__ meta, int kk, int gb)
{
  int pass = 4 + kk;
  int tile = gb >> 7;
  int kt   = gb & 127;
  if (tile >= meta[M_NTILES + pass]) return;
  int m0   = meta[M_TILE_M + pass * MAXTILES + tile];
  int e    = meta[M_TILE_E + pass * MAXTILES + tile];
  int sidx = pass * 8 + e;
  int cnt  = meta[M_COUNTS + sidx];
  int seg  = meta[M_OFFSETS + sidx];
  const int* stok = meta + M_STOK + 2 * 8192 + seg;
  size_t cb = ((size_t)tile * 128 + kt) * 4096;
  #pragma unroll
  for (int j = 0; j < 2; ++j) {
    int idx = threadIdx.x * 2 + j;
    int fq = idx >> 7, row = idx & 127;
    int m = m0 + row; if (m >= cnt) m = cnt - 1;
    f16x8 h = *(const f16x8*)(Gi + (size_t)stok[m] * I_DIM + kt * 32 + fq * 8);
    *(f16x8*)(Ad + cb + (size_t)idx * 8) = h;
  }
}

// parallel fusion (small-ws): convert Wg + gather_a
__global__ __launch_bounds__(256) void fused_cw3_ga(const float* __restrict__ W,
    _Float16* __restrict__ Whi, _Float16* __restrict__ Wlo,
    const float* __restrict__ X, _Float16* __restrict__ Atgt,
    const int* __restrict__ meta, int layer, int kk)
{
  __shared__ _Float16 sHi[8192];
  __shared__ _Float16 sLo[8192];
  int b = (int)blockIdx.x;
  if (b < CW3BLK) convert_lds_body<3, 32, 32>(W, Whi, Wlo, b, sHi, sLo);
  else gather_a_body(X, Atgt, meta, layer, kk, b - CW3BLK);
}

// parallel fusion (big-ws): convert Wg + convert Wu + gather_a(0,0)
__global__ __launch_bounds__(256) void fused_cw3x2_ga(
    const float* __restrict__ Wg, _Float16* __restrict__ Wgh, _Float16* __restrict__ Wgl,
    const float* __restrict__ Wu, _Float16* __restrict__ Wuh, _Float16* __restrict__ Wul,
    const float* __restrict__ X, _Float16* __restrict__ Atgt, const int* __restrict__ meta)
{
  __shared__ _Float16 sHi[8192];
  __shared__ _Float16 sLo[8192];
  int b = (int)blockIdx.x;
  if (b < CW3BLK) convert_lds_body<3, 32, 32>(Wg, Wgh, Wgl, b, sHi, sLo);
  else if (b < 2 * CW3BLK) convert_lds_body<3, 32, 32>(Wu, Wuh, Wul, b - CW3BLK, sHi, sLo);
  else gather_a_body(X, Atgt, meta, 0, 0, b - 2 * CW3BLK);
}

__global__ __launch_bounds__(256) void fused_cw1_gd(const float* __restrict__ W,
    _Float16* __restrict__ Whi,
    const _Float16* __restrict__ Gi, _Float16* __restrict__ Adt,
    const int* __restrict__ meta, int kk)
{
  __shared__ _Float16 sHi[8192];
  int b = (int)blockIdx.x;
  if (b < CW1BLK) convert_lds_body<1, 8, 128>(W, Whi, Whi, b, sHi, sHi);
  else gather_d_body(Gi, Adt, meta, kk, b - CW1BLK);
}

__global__ __launch_bounds__(256) void gather_a_k(const float* __restrict__ X,
    _Float16* __restrict__ Apass, const int* __restrict__ meta, int layer, int kk)
{
  gather_a_body(X, Apass, meta, layer, kk, (int)blockIdx.x);
}

__device__ __forceinline__ void gload16(const _Float16* g, _Float16* l) {
  __builtin_amdgcn_global_load_lds(
      (const __attribute__((address_space(1))) void*)g,
      (__attribute__((address_space(3))) void*)l, 16, 0, 0);
}

// Routed GEMM v9 + prologue work-stealing (r17/r18-proven).
template<int SPLITS, int ADD, int N, int NB, int STEPS, int SPLITK, int STEAL>
__global__ __launch_bounds__(256, 3) void moe_gemm9(
    const _Float16* __restrict__ Aimg,
    const _Float16* __restrict__ Whi, const _Float16* __restrict__ Wlo,
    float* __restrict__ Out, float* __restrict__ Scr,
    const int* __restrict__ meta, int layer, int kk,
    const void* __restrict__ aux_src, _Float16* __restrict__ aux_dst,
    int alayer, int akk)
{
  constexpr int NWG = MAXTILES * NB * SPLITK;
  constexpr int Q8  = NWG / 8;
  constexpr int WCH = (SPLITS == 3) ? 1 : 2;
  constexpr int NPER = GEMMBLK / 8;

  __shared__ __align__(16) _Float16 sA[3 * 8192];

  if constexpr (STEAL == 1) {
    for (int gb = (int)blockIdx.x; gb < MAXTILES * 32; gb += GEMMBLK)
      gather_a_body((const float*)aux_src, aux_dst, meta, alayer, akk, gb);
  } else if constexpr (STEAL == 2) {
    for (int gb = (int)blockIdx.x; gb < MAXTILES * 128; gb += GEMMBLK)
      gather_d_body((const _Float16*)aux_src, aux_dst, meta, akk, gb);
  }

  int xcd  = (int)blockIdx.x & 7;
  int slot = (int)blockIdx.x >> 3;
  int pass = layer * 2 + kk;
  int ntiles = meta[M_NTILES + pass];

  int tid = threadIdx.x, lane = tid & 63, w = tid >> 6;
  int wr = w >> 1, wc = w & 1, fr = lane & 15, fq = lane >> 4;
  int aoff = (fq * 128 + wr * 64 + fr) * 8;

  for (int base = slot; base < Q8; base += NPER) {
    int logical = xcd * Q8 + base;
    int kc = 0, rem = logical;
    if constexpr (SPLITK == 2) { kc = logical / (MAXTILES * NB); rem = logical - kc * (MAXTILES * NB); }
    int tx = rem / NB;
    int ny = rem - tx * NB;
    if (tx >= ntiles) continue;

    int e    = meta[M_TILE_E + pass * MAXTILES + tx];
    int m0   = meta[M_TILE_M + pass * MAXTILES + tx];
    int sidx = pass * 8 + e;
    int cnt  = meta[M_COUNTS + sidx];
    int seg  = meta[M_OFFSETS + sidx];
    int n0   = ny * 128;

    const int*   stok = meta + M_STOK + layer * 8192 + seg;
    const float* sprb = (const float*)meta + M_SPRB + layer * 8192 + seg;

    const _Float16* At = Aimg + ((size_t)tx * SPLITK + kc) * STEPS * 8192;
    size_t wpanel = (size_t)(e * NB + ny) * (STEPS * WCH * SPLITK) * 4096;
    int kb = kc * STEPS * WCH;
    const _Float16* WhL = Whi + wpanel + (size_t)kb * 4096 + (fq * 128 + wc * 64 + fr) * 8;
    const _Float16* WlL = Wlo + wpanel + (size_t)kb * 4096 + (fq * 128 + wc * 64 + fr) * 8;

    auto stageA = [&](int it, int slot2) {
      const _Float16* s0 = At + (size_t)it * 8192 + w * 1024 + lane * 8;
      _Float16* d0 = sA + slot2 * 8192 + w * 1024;
      gload16(s0,        d0);
      gload16(s0 + 512,  d0 + 512);
      gload16(s0 + 4096, d0 + 4096);
      gload16(s0 + 4608, d0 + 4608);
    };
    auto loadW = [&](int it, f16x8 (&wh)[WCH][4], f16x8 (&wl)[1][4]) {
      #pragma unroll
      for (int c = 0; c < WCH; ++c) {
        size_t cb = (size_t)(it * WCH + c) * 4096;
        #pragma unroll
        for (int ni = 0; ni < 4; ++ni) wh[c][ni] = *(const f16x8*)(WhL + cb + ni * 128);
      }
      if constexpr (SPLITS == 3) {
        size_t cb = (size_t)it * 4096;
        #pragma unroll
        for (int ni = 0; ni < 4; ++ni) wl[0][ni] = *(const f16x8*)(WlL + cb + ni * 128);
      }
    };

    f32x4 acc[4][4];
    #pragma unroll
    for (int i = 0; i < 4; ++i)
      #pragma unroll
      for (int j = 0; j < 4; ++j) acc[i][j] = f32x4{0.f, 0.f, 0.f, 0.f};

    f16x8 w0h[WCH][4], w0l[1][4], w1h[WCH][4], w1l[1][4];
    int rc = 0, rs = 2;

    auto step = [&](int it, f16x8 (&cwh)[WCH][4], f16x8 (&cwl)[1][4],
                    f16x8 (&nwh)[WCH][4], f16x8 (&nwl)[1][4]) {
      int it2 = (it + 2 < STEPS) ? it + 2 : STEPS - 1;
      int it1 = (it + 1 < STEPS) ? it + 1 : STEPS - 1;
      stageA(it2, rs);
      loadW(it1, nwh, nwl);
      __builtin_amdgcn_sched_barrier(0);

      const _Float16* A0 = sA + rc * 8192;
      __builtin_amdgcn_s_setprio(1);
      if constexpr (SPLITS == 3) {
        f16x8 ah[4], al[4];
        #pragma unroll
        for (int mi = 0; mi < 4; ++mi) ah[mi] = *(const f16x8*)(A0 + aoff + mi * 128);
        #pragma unroll
        for (int mi = 0; mi < 4; ++mi) al[mi] = *(const f16x8*)(A0 + 4096 + aoff + mi * 128);
        #pragma unroll
        for (int mi = 0; mi < 4; ++mi)
          #pragma unroll
          for (int ni = 0; ni < 4; ++ni)
            acc[mi][ni] = __builtin_amdgcn_mfma_f32_16x16x32_f16(ah[mi], cwh[0][ni], acc[mi][ni], 0, 0, 0);
        #pragma unroll
        for (int mi = 0; mi < 4; ++mi)
          #pragma unroll
          for (int ni = 0; ni < 4; ++ni)
            acc[mi][ni] = __builtin_amdgcn_mfma_f32_16x16x32_f16(ah[mi], cwl[0][ni], acc[mi][ni], 0, 0, 0);
        #pragma unroll
        for (int mi = 0; mi < 4; ++mi)
          #pragma unroll
          for (int ni = 0; ni < 4; ++ni)
            acc[mi][ni] = __builtin_amdgcn_mfma_f32_16x16x32_f16(al[mi], cwh[0][ni], acc[mi][ni], 0, 0, 0);
      } else {
        #pragma unroll
        for (int c = 0; c < WCH; ++c) {
          f16x8 ah[4];
          #pragma unroll
          for (int mi = 0; mi < 4; ++mi) ah[mi] = *(const f16x8*)(A0 + c * 4096 + aoff + mi * 128);
          #pragma unroll
          for (int mi = 0; mi < 4; ++mi)
            #pragma unroll
            for (int ni = 0; ni < 4; ++ni)
              acc[mi][ni] = __builtin_amdgcn_mfma_f32_16x16x32_f16(ah[mi], cwh[c][ni], acc[mi][ni], 0, 0, 0);
        }
      }
      __builtin_amdgcn_s_setprio(0);

      __builtin_amdgcn_sched_barrier(0);
      asm volatile("s_waitcnt vmcnt(12)" ::: "memory");
      __builtin_amdgcn_s_barrier();
      __builtin_amdgcn_sched_barrier(0);
      rc = (rc == 2) ? 0 : rc + 1;
      rs = (rs == 2) ? 0 : rs + 1;
    };

    asm volatile("s_waitcnt vmcnt(0)" ::: "memory");
    __builtin_amdgcn_s_barrier();
    stageA(0, 0);
    stageA(1 < STEPS ? 1 : 0, 1);
    loadW(0, w0h, w0l);
    __builtin_amdgcn_sched_barrier(0);
    asm volatile("s_waitcnt vmcnt(12)" ::: "memory");
    __builtin_amdgcn_s_barrier();
    __builtin_amdgcn_sched_barrier(0);

    for (int it = 0; it < STEPS; it += 2) {
      step(it,     w0h, w0l, w1h, w1l);
      step(it + 1, w1h, w1l, w0h, w0l);
    }

    float* dst = (SPLITK == 2 && kc == 1) ? Scr : Out;
    #pragma unroll
    for (int mi = 0; mi < 4; ++mi) {
      #pragma unroll
      for (int jj = 0; jj < 4; ++jj) {
        int lm = wr * 64 + mi * 16 + fq * 4 + jj;
        int gm = m0 + lm;
        if (gm < cnt) {
          int tok = stok[gm];
          float p = sprb[gm];
          float* orow = dst + (size_t)tok * N + n0 + wc * 64 + fr;
          #pragma unroll
          for (int ni = 0; ni < 4; ++ni) {
            float v = p * acc[mi][ni][jj];
            if constexpr (ADD) orow[ni * 16] += v; else orow[ni * 16] = v;
          }
        }
      }
    }
  }
}

// fused SwiGLU + down-router; f16 inter out (r15-proven)
__global__ __launch_bounds__(256) void swiglu_router(const float* __restrict__ g,
    const float* __restrict__ u, const float* __restrict__ Rd,
    _Float16* __restrict__ gi, int* __restrict__ meta)
{
  int t = blockIdx.x, tid = threadIdx.x;
  float part[8];
  #pragma unroll
  for (int e = 0; e < 8; ++e) part[e] = 0.f;
  const float* gr = g + (size_t)t * I_DIM;
  const float* ur = u + (size_t)t * I_DIM;
  _Float16*    ir = gi + (size_t)t * I_DIM;
  #pragma unroll
  for (int cc = 0; cc < 4; ++cc) {
    int i = cc * 1024 + tid * 4;
    f32x4 gv = *(const f32x4*)(gr + i);
    f32x4 uv = *(const f32x4*)(ur + i);
    f32x4 iv;
    f16x4 hv;
    #pragma unroll
    for (int j = 0; j < 4; ++j) {
      float xx = gv[j];
      iv[j] = (xx / (1.f + expf(-xx))) * uv[j];
      hv[j] = (_Float16)iv[j];
    }
    *(f16x4*)(ir + i) = hv;
    #pragma unroll
    for (int e = 0; e < 8; ++e) {
      f32x4 rv = *(const f32x4*)(Rd + (size_t)e * I_DIM + i);
      part[e] += rv[0]*iv[0] + rv[1]*iv[1] + rv[2]*iv[2] + rv[3]*iv[3];
    }
  }
  __shared__ float red[4][8];
  int w = tid >> 6, lane = tid & 63;
  #pragma unroll
  for (int e = 0; e < 8; ++e) {
    float s = wave_sum(part[e]);
    if (lane == 0) red[w][e] = s;
  }
  __syncthreads();
  if (tid == 0) {
    float lg[8];
    #pragma unroll
    for (int e = 0; e < 8; ++e) lg[e] = red[0][e] + red[1][e] + red[2][e] + red[3][e];
    topk_write(meta, 2, t, lg);
  }
}

__global__ __launch_bounds__(256) void combine_kernel(float* __restrict__ out,
                                                      const float* __restrict__ scr)
{
  int i = blockIdx.x * 1024 + threadIdx.x * 4;
  f32x4 a = *(const f32x4*)(out + i);
  f32x4 b = *(const f32x4*)(scr + i);
  #pragma unroll
  for (int j = 0; j < 4; ++j) a[j] += b[j];
  *(f32x4*)(out + i) = a;
}

extern "C" void kernel_launch(void* const* d_in, const int* in_sizes, int n_in,
                              void* d_out, int out_size, void* d_ws, size_t ws_size,
                              hipStream_t stream)
{
  const float* x  = (const float*)d_in[0];
  const float* Rg = (const float*)d_in[1];
  const float* Wg = (const float*)d_in[2];
  const float* Ru = (const float*)d_in[3];
  const float* Wu = (const float*)d_in[4];
  const float* Rd = (const float*)d_in[5];
  const float* Wd = (const float*)d_in[6];
  float* out = (float*)d_out;
  char* ws = (char*)d_ws;

  const size_t MB64 = 67108864;
  const size_t A_SZ = 20971520;

  if (ws_size >= (size_t)445644800) {
    // ---- big-ws path: de-aliased W planes + third A image (13 dispatches) ----
    _Float16* Wgh = (_Float16*)ws;
    _Float16* Wgl = (_Float16*)(ws + MB64);
    _Float16* Wuh = (_Float16*)(ws + 2 * MB64);
    _Float16* Wul = (_Float16*)(ws + 3 * MB64);
    float* g = (float*)(ws + 4 * MB64);
    float* u = (float*)(ws + 5 * MB64);
    int* meta = (int*)(ws + 6 * MB64);
    _Float16* A0 = (_Float16*)(ws + 6 * MB64 + 1048576);
    _Float16* A2 = (_Float16*)(ws + 6 * MB64 + 1048576 + A_SZ);
    _Float16* A1  = (_Float16*)u;      // dead until gemm(1,0) writes u
    _Float16* gi  = (_Float16*)Wgl;    // Wg planes dead after layer-0 gemms
    _Float16* Wdh = Wgh;               // Wd f16 image in dead Wgh
    _Float16* Ad0 = (_Float16*)u;      // u dead after swiglu
    _Float16* Ad1 = (_Float16*)g;      // g dead after swiglu
    float* dscr   = (float*)A0;        // A0 dead in down phase

    router_gu<<<dim3(T_NUM / 4), 256, 0, stream>>>(x, Rg, Ru, meta);
    route_finalize<<<dim3(1), 256, 0, stream>>>(meta, 0, 2);

    fused_cw3x2_ga<<<dim3(2 * CW3BLK + MAXTILES * 32), 256, 0, stream>>>(
        Wg, Wgh, Wgl, Wu, Wuh, Wul, x, A0, meta);
    moe_gemm9<3, 0, I_DIM, 32, 32, 1, 1><<<dim3(GEMMBLK), 256, 0, stream>>>(
        A0, Wgh, Wgl, g, g, meta, 0, 0, x, A1, 0, 1);
    moe_gemm9<3, 1, I_DIM, 32, 32, 1, 1><<<dim3(GEMMBLK), 256, 0, stream>>>(
        A1, Wgh, Wgl, g, g, meta, 0, 1, x, A0, 1, 0);
    moe_gemm9<3, 0, I_DIM, 32, 32, 1, 1><<<dim3(GEMMBLK), 256, 0, stream>>>(
        A0, Wuh, Wul, u, u, meta, 1, 0, x, A2, 1, 1);
    moe_gemm9<3, 1, I_DIM, 32, 32, 1, 0><<<dim3(GEMMBLK), 256, 0, stream>>>(
        A2, Wuh, Wul, u, u, meta, 1, 1, x, A2, 0, 0);

    swiglu_router<<<dim3(T_NUM), 256, 0, stream>>>(g, u, Rd, gi, meta);
    route_finalize<<<dim3(1), 256, 0, stream>>>(meta, 2, 1);

    fused_cw1_gd<<<dim3(CW1BLK + MAXTILES * 128), 256, 0, stream>>>(Wd, Wdh, gi, Ad0, meta, 0);
    moe_gemm9<1, 0, H_DIM, 8, 32, 2, 2><<<dim3(GEMMBLK), 256, 0, stream>>>(
        Ad0, Wdh, Wdh, out, dscr, meta, 2, 0, gi, Ad1, 0, 1);
    moe_gemm9<1, 1, H_DIM, 8, 32, 2, 0><<<dim3(GEMMBLK), 256, 0, stream>>>(
        Ad1, Wdh, Wdh, out, dscr, meta, 2, 1, gi, Ad1, 0, 1);
    combine_kernel<<<dim3(T_NUM), 256, 0, stream>>>(out, dscr);
  } else {
    // ---- small-ws fallback: r17 sequence, LDS-staged convert ----
    _Float16* Wth = (_Float16*)ws;
    _Float16* Wtl = (_Float16*)(ws + MB64);
    float* g   = (float*)(ws + (size_t)134217728);
    float* u   = (float*)(ws + (size_t)201326592);
    int*  meta = (int*)(ws + (size_t)268435456);
    _Float16* A0 = (_Float16*)(ws + (size_t)269484032);
    _Float16* A1 = (_Float16*)u;
    _Float16* gi = (_Float16*)Wtl;
    _Float16* Ad0 = (_Float16*)u;
    _Float16* Ad1 = (_Float16*)g;
    float* dscr = (float*)A0;

    router_gu<<<dim3(T_NUM / 4), 256, 0, stream>>>(x, Rg, Ru, meta);
    route_finalize<<<dim3(1), 256, 0, stream>>>(meta, 0, 2);

    fused_cw3_ga<<<dim3(CW3BLK + MAXTILES * 32), 256, 0, stream>>>(Wg, Wth, Wtl, x, A0, meta, 0, 0);
    moe_gemm9<3, 0, I_DIM, 32, 32, 1, 1><<<dim3(GEMMBLK), 256, 0, stream>>>(
        A0, Wth, Wtl, g, g, meta, 0, 0, x, A1, 0, 1);
    moe_gemm9<3, 1, I_DIM, 32, 32, 1, 1><<<dim3(GEMMBLK), 256, 0, stream>>>(
        A1, Wth, Wtl, g, g, meta, 0, 1, x, A0, 1, 0);
    fused_cw3_ga<<<dim3(CW3BLK), 256, 0, stream>>>(Wu, Wth, Wtl, x, A0, meta, 0, 0);
    moe_gemm9<3, 0, I_DIM, 32, 32, 1, 0><<<dim3(GEMMBLK), 256, 0, stream>>>(
        A0, Wth, Wtl, u, u, meta, 1, 0, x, A0, 0, 0);
    gather_a_k<<<dim3(MAXTILES * 32), 256, 0, stream>>>(x, A0, meta, 1, 1);
    moe_gemm9<3, 1, I_DIM, 32, 32, 1, 0><<<dim3(GEMMBLK), 256, 0, stream>>>(
        A0, Wth, Wtl, u, u, meta, 1, 1, x, A0, 0, 0);

    swiglu_router<<<dim3(T_NUM), 256, 0, stream>>>(g, u, Rd, gi, meta);
    route_finalize<<<dim3(1), 256, 0, stream>>>(meta, 2, 1);

    fused_cw1_gd<<<dim3(CW1BLK + MAXTILES * 128), 256, 0, stream>>>(Wd, Wth, gi, Ad0, meta, 0);
    moe_gemm9<1, 0, H_DIM, 8, 32, 2, 2><<<dim3(GEMMBLK), 256, 0, stream>>>(
        Ad0, Wth, Wth, out, dscr, meta, 2, 0, gi, Ad1, 0, 1);
    moe_gemm9<1, 1, H_DIM, 8, 32, 2, 0><<<dim3(GEMMBLK), 256, 0, stream>>>(
        Ad1, Wth, Wth, out, dscr, meta, 2, 1, gi, Ad1, 0, 1);
    combine_kernel<<<dim3(T_NUM), 256, 0, stream>>>(out, dscr);
  }
}

// Round 22
// 926.343 us; speedup vs baseline: 1.1570x; 1.0101x over previous
//
#include <hip/hip_runtime.h>
#include <cmath>

typedef float    f32x4 __attribute__((ext_vector_type(4)));
typedef _Float16 f16x8 __attribute__((ext_vector_type(8)));
typedef _Float16 f16x4 __attribute__((ext_vector_type(4)));

#define T_NUM 4096
#define H_DIM 1024
#define I_DIM 4096
#define MAXTILES 40
#define GEMMBLK 768
#define CW3BLK 4096
#define CW1BLK 4096
#define GDBLK  5120   // MAXTILES*128

// ---- meta layout ----
#define M_COUNTS   0
#define M_CURSORS  48
#define M_OFFSETS  96
#define M_NTILES   144
#define M_TILE_E   152
#define M_TILE_M   392
#define M_TOPKI    1024
#define M_TOPKP    25600
#define M_STOK     50176
#define M_SPRB     74752

__device__ __forceinline__ float wave_sum(float v) {
  v += __shfl_xor(v, 32);
  v += __shfl_xor(v, 16);
  v += __shfl_xor(v, 8);
  v += __shfl_xor(v, 4);
  v += __shfl_xor(v, 2);
  v += __shfl_xor(v, 1);
  return v;
}

__device__ __forceinline__ void topk_write(int* meta, int layer, int t, const float* v) {
  int e0 = 0; float v0 = v[0];
  #pragma unroll
  for (int e = 1; e < 8; ++e) { if (v[e] > v0) { v0 = v[e]; e0 = e; } }
  int e1 = 0; float v1 = -3.4e38f;
  #pragma unroll
  for (int e = 0; e < 8; ++e) { if (e != e0 && v[e] > v1) { v1 = v[e]; e1 = e; } }
  float ex = expf(v1 - v0);
  float p0 = 1.f / (1.f + ex);
  float p1 = ex / (1.f + ex);
  meta[M_TOPKI + (layer * T_NUM + t) * 2    ] = e0;
  meta[M_TOPKI + (layer * T_NUM + t) * 2 + 1] = e1;
  ((float*)meta)[M_TOPKP + (layer * T_NUM + t) * 2    ] = p0;
  ((float*)meta)[M_TOPKP + (layer * T_NUM + t) * 2 + 1] = p1;
}

__global__ __launch_bounds__(256) void router_gu(const float* __restrict__ x,
    const float* __restrict__ Rg, const float* __restrict__ Ru, int* __restrict__ meta)
{
  int w = threadIdx.x >> 6, lane = threadIdx.x & 63;
  int t = blockIdx.x * 4 + w;
  const float* xr = x + (size_t)t * H_DIM + lane * 4;
  f32x4 xv[4];
  #pragma unroll
  for (int c = 0; c < 4; ++c) xv[c] = *(const f32x4*)(xr + c * 256);
  float lg[8], lu[8];
  #pragma unroll
  for (int e = 0; e < 8; ++e) {
    const float* rg = Rg + (size_t)e * H_DIM + lane * 4;
    const float* ru = Ru + (size_t)e * H_DIM + lane * 4;
    float sg = 0.f, su = 0.f;
    #pragma unroll
    for (int c = 0; c < 4; ++c) {
      f32x4 a = *(const f32x4*)(rg + c * 256);
      f32x4 b = *(const f32x4*)(ru + c * 256);
      sg += a[0]*xv[c][0] + a[1]*xv[c][1] + a[2]*xv[c][2] + a[3]*xv[c][3];
      su += b[0]*xv[c][0] + b[1]*xv[c][1] + b[2]*xv[c][2] + b[3]*xv[c][3];
    }
    lg[e] = wave_sum(sg);
    lu[e] = wave_sum(su);
  }
  if (lane == 0) {
    topk_write(meta, 0, t, lg);
    topk_write(meta, 1, t, lu);
  }
}

__global__ __launch_bounds__(256) void route_finalize(int* __restrict__ meta, int l0, int nl) {
  __shared__ int cnt_s[32];
  __shared__ int off_s[32];
  __shared__ int cur_s[32];
  int tid = threadIdx.x;
  if (tid < 32) { cnt_s[tid] = 0; cur_s[tid] = 0; }
  __syncthreads();
  for (int t = tid; t < T_NUM; t += 256) {
    for (int l = l0; l < l0 + nl; ++l) {
      int li = l - l0;
      #pragma unroll
      for (int k = 0; k < 2; ++k) {
        int e = meta[M_TOPKI + (l * T_NUM + t) * 2 + k];
        atomicAdd(&cnt_s[li * 16 + k * 8 + e], 1);
      }
    }
  }
  __syncthreads();
  if (tid == 0) {
    for (int l = l0; l < l0 + nl; ++l) {
      int li = l - l0;
      int off = 0;
      for (int k = 0; k < 2; ++k) {
        int nt = 0;
        for (int e = 0; e < 8; ++e) {
          int s = (l * 2 + k) * 8 + e;
          int c = cnt_s[li * 16 + k * 8 + e];
          meta[M_COUNTS + s] = c;
          meta[M_OFFSETS + s] = off;
          off_s[li * 16 + k * 8 + e] = off;
          for (int m = 0; m < c; m += 128) {
            meta[M_TILE_E + (l * 2 + k) * MAXTILES + nt] = e;
            meta[M_TILE_M + (l * 2 + k) * MAXTILES + nt] = m;
            ++nt;
          }
          off += c;
        }
        meta[M_NTILES + l * 2 + k] = nt;
      }
    }
  }
  __syncthreads();
  for (int t = tid; t < T_NUM; t += 256) {
    for (int l = l0; l < l0 + nl; ++l) {
      int li = l - l0;
      #pragma unroll
      for (int k = 0; k < 2; ++k) {
        int e = meta[M_TOPKI + (l * T_NUM + t) * 2 + k];
        float p = ((float*)meta)[M_TOPKP + (l * T_NUM + t) * 2 + k];
        int si = li * 16 + k * 8 + e;
        int pos = off_s[si] + atomicAdd(&cur_s[si], 1);
        meta[M_STOK + l * 8192 + pos] = t;
        ((float*)meta)[M_SPRB + l * 8192 + pos] = p;
      }
    }
  }
}

// ---- LDS-staged W convert (r21-proven) ----
template<int SPLITS, int NB, int KT>
__device__ __forceinline__ void convert_lds_body(const float* __restrict__ W,
    _Float16* __restrict__ Whi, _Float16* __restrict__ Wlo, int blk,
    _Float16* sHi, _Float16* sLo)
{
  constexpr int KTG = KT / 2;
  constexpr int K   = KT * 32;
  int panel = blk / KTG;
  int ktg   = blk - panel * KTG;
  int t = threadIdx.x;
  int r = t >> 1, h = t & 1;

  const float* src = W + ((size_t)panel * 128 + r) * K + (ktg * 2 + h) * 32;
  f32x4 v[8];
  #pragma unroll
  for (int j = 0; j < 8; ++j) v[j] = *(const f32x4*)(src + j * 4);

  #pragma unroll
  for (int fq = 0; fq < 4; ++fq) {
    f16x8 hi8, lo8;
    #pragma unroll
    for (int q = 0; q < 8; ++q) {
      int idx = fq * 8 + q;
      float x = v[idx >> 2][idx & 3];
      _Float16 hx = (_Float16)x;
      hi8[q] = hx;
      if constexpr (SPLITS == 3) lo8[q] = (_Float16)(x - (float)hx);
    }
    int loff = h * 4096 + fq * 1024 + r * 8;
    *(f16x8*)(sHi + loff) = hi8;
    if constexpr (SPLITS == 3) *(f16x8*)(sLo + loff) = lo8;
  }
  __syncthreads();

  size_t base = ((size_t)panel * KT + ktg * 2) * 4096;
  #pragma unroll
  for (int j = 0; j < 4; ++j) {
    int o = (j * 256 + t) * 8;
    *(f16x8*)(Whi + base + o) = *(const f16x8*)(sHi + o);
  }
  if constexpr (SPLITS == 3) {
    #pragma unroll
    for (int j = 0; j < 4; ++j) {
      int o = (j * 256 + t) * 8;
      *(f16x8*)(Wlo + base + o) = *(const f16x8*)(sLo + o);
    }
  }
}

__device__ __forceinline__ void gather_a_body(const float* __restrict__ X,
    _Float16* __restrict__ Apass, const int* __restrict__ meta, int layer, int kk, int gb)
{
  int pass = layer * 2 + kk;
  int tile = gb >> 5;
  int kt   = gb & 31;
  if (tile >= meta[M_NTILES + pass]) return;
  int m0   = meta[M_TILE_M + pass * MAXTILES + tile];
  int e    = meta[M_TILE_E + pass * MAXTILES + tile];
  int sidx = pass * 8 + e;
  int cnt  = meta[M_COUNTS + sidx];
  int seg  = meta[M_OFFSETS + sidx];
  const int* stok = meta + M_STOK + layer * 8192 + seg;
  size_t cb = ((size_t)tile * 32 + kt) * 8192;
  #pragma unroll
  for (int j = 0; j < 2; ++j) {
    int idx = threadIdx.x * 2 + j;
    int fq = idx >> 7, row = idx & 127;
    int m = m0 + row; if (m >= cnt) m = cnt - 1;
    const float* src = X + (size_t)stok[m] * H_DIM + kt * 32 + fq * 8;
    f32x4 v0 = *(const f32x4*)src;
    f32x4 v1 = *(const f32x4*)(src + 4);
    f16x8 h, l;
    #pragma unroll
    for (int q = 0; q < 8; ++q) {
      float v = (q < 4) ? v0[q] : v1[q - 4];
      _Float16 hv = (_Float16)v;
      h[q] = hv;
      l[q] = (_Float16)(v - (float)hv);
    }
    *(f16x8*)(Apass + cb + (size_t)idx * 8) = h;
    *(f16x8*)(Apass + cb + 4096 + (size_t)idx * 8) = l;
  }
}

__device__ __forceinline__ void gather_d_body(const _Float16* __restrict__ Gi,
    _Float16* __restrict__ Ad, const int* __restrict__ meta, int kk, int gb)
{
  int pass = 4 + kk;
  int tile = gb >> 7;
  int kt   = gb & 127;
  if (tile >= meta[M_NTILES + pass]) return;
  int m0   = meta[M_TILE_M + pass * MAXTILES + tile];
  int e    = meta[M_TILE_E + pass * MAXTILES + tile];
  int sidx = pass * 8 + e;
  int cnt  = meta[M_COUNTS + sidx];
  int seg  = meta[M_OFFSETS + sidx];
  const int* stok = meta + M_STOK + 2 * 8192 + seg;
  size_t cb = ((size_t)tile * 128 + kt) * 4096;
  #pragma unroll
  for (int j = 0; j < 2; ++j) {
    int idx = threadIdx.x * 2 + j;
    int fq = idx >> 7, row = idx & 127;
    int m = m0 + row; if (m >= cnt) m = cnt - 1;
    f16x8 h = *(const f16x8*)(Gi + (size_t)stok[m] * I_DIM + kt * 32 + fq * 8);
    *(f16x8*)(Ad + cb + (size_t)idx * 8) = h;
  }
}

// parallel fusion (small-ws): convert Wg + gather_a
__global__ __launch_bounds__(256) void fused_cw3_ga(const float* __restrict__ W,
    _Float16* __restrict__ Whi, _Float16* __restrict__ Wlo,
    const float* __restrict__ X, _Float16* __restrict__ Atgt,
    const int* __restrict__ meta, int layer, int kk)
{
  __shared__ _Float16 sHi[8192];
  __shared__ _Float16 sLo[8192];
  int b = (int)blockIdx.x;
  if (b < CW3BLK) convert_lds_body<3, 32, 32>(W, Whi, Wlo, b, sHi, sLo);
  else gather_a_body(X, Atgt, meta, layer, kk, b - CW3BLK);
}

// parallel fusion (big-ws): convert Wg + convert Wu + gather_a(0,0)
__global__ __launch_bounds__(256) void fused_cw3x2_ga(
    const float* __restrict__ Wg, _Float16* __restrict__ Wgh, _Float16* __restrict__ Wgl,
    const float* __restrict__ Wu, _Float16* __restrict__ Wuh, _Float16* __restrict__ Wul,
    const float* __restrict__ X, _Float16* __restrict__ Atgt, const int* __restrict__ meta)
{
  __shared__ _Float16 sHi[8192];
  __shared__ _Float16 sLo[8192];
  int b = (int)blockIdx.x;
  if (b < CW3BLK) convert_lds_body<3, 32, 32>(Wg, Wgh, Wgl, b, sHi, sLo);
  else if (b < 2 * CW3BLK) convert_lds_body<3, 32, 32>(Wu, Wuh, Wul, b - CW3BLK, sHi, sLo);
  else gather_a_body(X, Atgt, meta, 0, 0, b - 2 * CW3BLK);
}

// convert Wd + gather D(0)->Ad0 (+ gather D(1)->Ad1 when grid covers it)
__global__ __launch_bounds__(256) void fused_cw1_gd(const float* __restrict__ W,
    _Float16* __restrict__ Whi,
    const _Float16* __restrict__ Gi, _Float16* __restrict__ Adt0,
    _Float16* __restrict__ Adt1, const int* __restrict__ meta)
{
  __shared__ _Float16 sHi[8192];
  int b = (int)blockIdx.x;
  if (b < CW1BLK) convert_lds_body<1, 8, 128>(W, Whi, Whi, b, sHi, sHi);
  else if (b < CW1BLK + GDBLK) gather_d_body(Gi, Adt0, meta, 0, b - CW1BLK);
  else gather_d_body(Gi, Adt1, meta, 1, b - CW1BLK - GDBLK);
}

__global__ __launch_bounds__(256) void gather_a_k(const float* __restrict__ X,
    _Float16* __restrict__ Apass, const int* __restrict__ meta, int layer, int kk)
{
  gather_a_body(X, Apass, meta, layer, kk, (int)blockIdx.x);
}

__device__ __forceinline__ void gload16(const _Float16* g, _Float16* l) {
  __builtin_amdgcn_global_load_lds(
      (const __attribute__((address_space(1))) void*)g,
      (__attribute__((address_space(3))) void*)l, 16, 0, 0);
}

// Routed GEMM v9 + prologue work-stealing (r17-r21 proven).
template<int SPLITS, int ADD, int N, int NB, int STEPS, int SPLITK, int STEAL>
__global__ __launch_bounds__(256, 3) void moe_gemm9(
    const _Float16* __restrict__ Aimg,
    const _Float16* __restrict__ Whi, const _Float16* __restrict__ Wlo,
    float* __restrict__ Out, float* __restrict__ Scr,
    const int* __restrict__ meta, int layer, int kk,
    const void* __restrict__ aux_src, _Float16* __restrict__ aux_dst,
    int alayer, int akk)
{
  constexpr int NWG = MAXTILES * NB * SPLITK;
  constexpr int Q8  = NWG / 8;
  constexpr int WCH = (SPLITS == 3) ? 1 : 2;
  constexpr int NPER = GEMMBLK / 8;

  __shared__ __align__(16) _Float16 sA[3 * 8192];

  if constexpr (STEAL == 1) {
    for (int gb = (int)blockIdx.x; gb < MAXTILES * 32; gb += GEMMBLK)
      gather_a_body((const float*)aux_src, aux_dst, meta, alayer, akk, gb);
  } else if constexpr (STEAL == 2) {
    for (int gb = (int)blockIdx.x; gb < MAXTILES * 128; gb += GEMMBLK)
      gather_d_body((const _Float16*)aux_src, aux_dst, meta, akk, gb);
  }

  int xcd  = (int)blockIdx.x & 7;
  int slot = (int)blockIdx.x >> 3;
  int pass = layer * 2 + kk;
  int ntiles = meta[M_NTILES + pass];

  int tid = threadIdx.x, lane = tid & 63, w = tid >> 6;
  int wr = w >> 1, wc = w & 1, fr = lane & 15, fq = lane >> 4;
  int aoff = (fq * 128 + wr * 64 + fr) * 8;

  for (int base = slot; base < Q8; base += NPER) {
    int logical = xcd * Q8 + base;
    int kc = 0, rem = logical;
    if constexpr (SPLITK == 2) { kc = logical / (MAXTILES * NB); rem = logical - kc * (MAXTILES * NB); }
    int tx = rem / NB;
    int ny = rem - tx * NB;
    if (tx >= ntiles) continue;

    int e    = meta[M_TILE_E + pass * MAXTILES + tx];
    int m0   = meta[M_TILE_M + pass * MAXTILES + tx];
    int sidx = pass * 8 + e;
    int cnt  = meta[M_COUNTS + sidx];
    int seg  = meta[M_OFFSETS + sidx];
    int n0   = ny * 128;

    const int*   stok = meta + M_STOK + layer * 8192 + seg;
    const float* sprb = (const float*)meta + M_SPRB + layer * 8192 + seg;

    const _Float16* At = Aimg + ((size_t)tx * SPLITK + kc) * STEPS * 8192;
    size_t wpanel = (size_t)(e * NB + ny) * (STEPS * WCH * SPLITK) * 4096;
    int kb = kc * STEPS * WCH;
    const _Float16* WhL = Whi + wpanel + (size_t)kb * 4096 + (fq * 128 + wc * 64 + fr) * 8;
    const _Float16* WlL = Wlo + wpanel + (size_t)kb * 4096 + (fq * 128 + wc * 64 + fr) * 8;

    auto stageA = [&](int it, int slot2) {
      const _Float16* s0 = At + (size_t)it * 8192 + w * 1024 + lane * 8;
      _Float16* d0 = sA + slot2 * 8192 + w * 1024;
      gload16(s0,        d0);
      gload16(s0 + 512,  d0 + 512);
      gload16(s0 + 4096, d0 + 4096);
      gload16(s0 + 4608, d0 + 4608);
    };
    auto loadW = [&](int it, f16x8 (&wh)[WCH][4], f16x8 (&wl)[1][4]) {
      #pragma unroll
      for (int c = 0; c < WCH; ++c) {
        size_t cb = (size_t)(it * WCH + c) * 4096;
        #pragma unroll
        for (int ni = 0; ni < 4; ++ni) wh[c][ni] = *(const f16x8*)(WhL + cb + ni * 128);
      }
      if constexpr (SPLITS == 3) {
        size_t cb = (size_t)it * 4096;
        #pragma unroll
        for (int ni = 0; ni < 4; ++ni) wl[0][ni] = *(const f16x8*)(WlL + cb + ni * 128);
      }
    };

    f32x4 acc[4][4];
    #pragma unroll
    for (int i = 0; i < 4; ++i)
      #pragma unroll
      for (int j = 0; j < 4; ++j) acc[i][j] = f32x4{0.f, 0.f, 0.f, 0.f};

    f16x8 w0h[WCH][4], w0l[1][4], w1h[WCH][4], w1l[1][4];
    int rc = 0, rs = 2;

    auto step = [&](int it, f16x8 (&cwh)[WCH][4], f16x8 (&cwl)[1][4],
                    f16x8 (&nwh)[WCH][4], f16x8 (&nwl)[1][4]) {
      int it2 = (it + 2 < STEPS) ? it + 2 : STEPS - 1;
      int it1 = (it + 1 < STEPS) ? it + 1 : STEPS - 1;
      stageA(it2, rs);
      loadW(it1, nwh, nwl);
      __builtin_amdgcn_sched_barrier(0);

      const _Float16* A0 = sA + rc * 8192;
      __builtin_amdgcn_s_setprio(1);
      if constexpr (SPLITS == 3) {
        f16x8 ah[4], al[4];
        #pragma unroll
        for (int mi = 0; mi < 4; ++mi) ah[mi] = *(const f16x8*)(A0 + aoff + mi * 128);
        #pragma unroll
        for (int mi = 0; mi < 4; ++mi) al[mi] = *(const f16x8*)(A0 + 4096 + aoff + mi * 128);
        #pragma unroll
        for (int mi = 0; mi < 4; ++mi)
          #pragma unroll
          for (int ni = 0; ni < 4; ++ni)
            acc[mi][ni] = __builtin_amdgcn_mfma_f32_16x16x32_f16(ah[mi], cwh[0][ni], acc[mi][ni], 0, 0, 0);
        #pragma unroll
        for (int mi = 0; mi < 4; ++mi)
          #pragma unroll
          for (int ni = 0; ni < 4; ++ni)
            acc[mi][ni] = __builtin_amdgcn_mfma_f32_16x16x32_f16(ah[mi], cwl[0][ni], acc[mi][ni], 0, 0, 0);
        #pragma unroll
        for (int mi = 0; mi < 4; ++mi)
          #pragma unroll
          for (int ni = 0; ni < 4; ++ni)
            acc[mi][ni] = __builtin_amdgcn_mfma_f32_16x16x32_f16(al[mi], cwh[0][ni], acc[mi][ni], 0, 0, 0);
      } else {
        #pragma unroll
        for (int c = 0; c < WCH; ++c) {
          f16x8 ah[4];
          #pragma unroll
          for (int mi = 0; mi < 4; ++mi) ah[mi] = *(const f16x8*)(A0 + c * 4096 + aoff + mi * 128);
          #pragma unroll
          for (int mi = 0; mi < 4; ++mi)
            #pragma unroll
            for (int ni = 0; ni < 4; ++ni)
              acc[mi][ni] = __builtin_amdgcn_mfma_f32_16x16x32_f16(ah[mi], cwh[c][ni], acc[mi][ni], 0, 0, 0);
        }
      }
      __builtin_amdgcn_s_setprio(0);

      __builtin_amdgcn_sched_barrier(0);
      asm volatile("s_waitcnt vmcnt(12)" ::: "memory");
      __builtin_amdgcn_s_barrier();
      __builtin_amdgcn_sched_barrier(0);
      rc = (rc == 2) ? 0 : rc + 1;
      rs = (rs == 2) ? 0 : rs + 1;
    };

    asm volatile("s_waitcnt vmcnt(0)" ::: "memory");
    __builtin_amdgcn_s_barrier();
    stageA(0, 0);
    stageA(1 < STEPS ? 1 : 0, 1);
    loadW(0, w0h, w0l);
    __builtin_amdgcn_sched_barrier(0);
    asm volatile("s_waitcnt vmcnt(12)" ::: "memory");
    __builtin_amdgcn_s_barrier();
    __builtin_amdgcn_sched_barrier(0);

    for (int it = 0; it < STEPS; it += 2) {
      step(it,     w0h, w0l, w1h, w1l);
      step(it + 1, w1h, w1l, w0h, w0l);
    }

    float* dst = (SPLITK == 2 && kc == 1) ? Scr : Out;
    #pragma unroll
    for (int mi = 0; mi < 4; ++mi) {
      #pragma unroll
      for (int jj = 0; jj < 4; ++jj) {
        int lm = wr * 64 + mi * 16 + fq * 4 + jj;
        int gm = m0 + lm;
        if (gm < cnt) {
          int tok = stok[gm];
          float p = sprb[gm];
          float* orow = dst + (size_t)tok * N + n0 + wc * 64 + fr;
          #pragma unroll
          for (int ni = 0; ni < 4; ++ni) {
            float v = p * acc[mi][ni][jj];
            if constexpr (ADD) orow[ni * 16] += v; else orow[ni * 16] = v;
          }
        }
      }
    }
  }
}

// Merged down GEMM (big-ws): BOTH k-passes in one dispatch; every (k,kc)
// combo stores to its own [T,1024] f32 buffer (no RMW, no ordering).
__global__ __launch_bounds__(256, 3) void moe_gemm_dn(
    const _Float16* __restrict__ Ad0, const _Float16* __restrict__ Ad1,
    const _Float16* __restrict__ Whi,
    float* __restrict__ Db, const int* __restrict__ meta)
{
  constexpr int NB = 8, STEPS = 32, WCH = 2;
  constexpr int NWG = MAXTILES * NB * 2;   // 640 per k-pass
  constexpr int Q16 = (2 * NWG) / 8;       // 160 per XCD
  constexpr int NPER = GEMMBLK / 8;

  __shared__ __align__(16) _Float16 sA[3 * 8192];

  int xcd  = (int)blockIdx.x & 7;
  int slot = (int)blockIdx.x >> 3;

  int tid = threadIdx.x, lane = tid & 63, w = tid >> 6;
  int wr = w >> 1, wc = w & 1, fr = lane & 15, fq = lane >> 4;
  int aoff = (fq * 128 + wr * 64 + fr) * 8;

  for (int base = slot; base < Q16; base += NPER) {
    int logical = xcd * Q16 + base;
    int kkp  = logical / NWG;
    int rem  = logical - kkp * NWG;
    int kc   = rem / (MAXTILES * NB);
    int rem2 = rem - kc * (MAXTILES * NB);
    int tx = rem2 / NB;
    int ny = rem2 - tx * NB;
    int pass = 4 + kkp;
    if (tx >= meta[M_NTILES + pass]) continue;

    int e    = meta[M_TILE_E + pass * MAXTILES + tx];
    int m0   = meta[M_TILE_M + pass * MAXTILES + tx];
    int sidx = pass * 8 + e;
    int cnt  = meta[M_COUNTS + sidx];
    int seg  = meta[M_OFFSETS + sidx];
    int n0   = ny * 128;

    const int*   stok = meta + M_STOK + 2 * 8192 + seg;
    const float* sprb = (const float*)meta + M_SPRB + 2 * 8192 + seg;

    const _Float16* Aimg = kkp ? Ad1 : Ad0;
    const _Float16* At = Aimg + ((size_t)tx * 2 + kc) * STEPS * 8192;
    size_t wpanel = (size_t)(e * NB + ny) * (STEPS * WCH * 2) * 4096;
    int kb = kc * STEPS * WCH;
    const _Float16* WhL = Whi + wpanel + (size_t)kb * 4096 + (fq * 128 + wc * 64 + fr) * 8;

    auto stageA = [&](int it, int slot2) {
      const _Float16* s0 = At + (size_t)it * 8192 + w * 1024 + lane * 8;
      _Float16* d0 = sA + slot2 * 8192 + w * 1024;
      gload16(s0,        d0);
      gload16(s0 + 512,  d0 + 512);
      gload16(s0 + 4096, d0 + 4096);
      gload16(s0 + 4608, d0 + 4608);
    };
    auto loadW = [&](int it, f16x8 (&wh)[WCH][4]) {
      #pragma unroll
      for (int c = 0; c < WCH; ++c) {
        size_t cb = (size_t)(it * WCH + c) * 4096;
        #pragma unroll
        for (int ni = 0; ni < 4; ++ni) wh[c][ni] = *(const f16x8*)(WhL + cb + ni * 128);
      }
    };

    f32x4 acc[4][4];
    #pragma unroll
    for (int i = 0; i < 4; ++i)
      #pragma unroll
      for (int j = 0; j < 4; ++j) acc[i][j] = f32x4{0.f, 0.f, 0.f, 0.f};

    f16x8 w0h[WCH][4], w1h[WCH][4];
    int rc = 0, rs = 2;

    auto step = [&](int it, f16x8 (&cwh)[WCH][4], f16x8 (&nwh)[WCH][4]) {
      int it2 = (it + 2 < STEPS) ? it + 2 : STEPS - 1;
      int it1 = (it + 1 < STEPS) ? it + 1 : STEPS - 1;
      stageA(it2, rs);
      loadW(it1, nwh);
      __builtin_amdgcn_sched_barrier(0);

      const _Float16* A0 = sA + rc * 8192;
      __builtin_amdgcn_s_setprio(1);
      #pragma unroll
      for (int c = 0; c < WCH; ++c) {
        f16x8 ah[4];
        #pragma unroll
        for (int mi = 0; mi < 4; ++mi) ah[mi] = *(const f16x8*)(A0 + c * 4096 + aoff + mi * 128);
        #pragma unroll
        for (int mi = 0; mi < 4; ++mi)
          #pragma unroll
          for (int ni = 0; ni < 4; ++ni)
            acc[mi][ni] = __builtin_amdgcn_mfma_f32_16x16x32_f16(ah[mi], cwh[c][ni], acc[mi][ni], 0, 0, 0);
      }
      __builtin_amdgcn_s_setprio(0);

      __builtin_amdgcn_sched_barrier(0);
      asm volatile("s_waitcnt vmcnt(12)" ::: "memory");
      __builtin_amdgcn_s_barrier();
      __builtin_amdgcn_sched_barrier(0);
      rc = (rc == 2) ? 0 : rc + 1;
      rs = (rs == 2) ? 0 : rs + 1;
    };

    asm volatile("s_waitcnt vmcnt(0)" ::: "memory");
    __builtin_amdgcn_s_barrier();
    stageA(0, 0);
    stageA(1, 1);
    loadW(0, w0h);
    __builtin_amdgcn_sched_barrier(0);
    asm volatile("s_waitcnt vmcnt(12)" ::: "memory");
    __builtin_amdgcn_s_barrier();
    __builtin_amdgcn_sched_barrier(0);

    for (int it = 0; it < STEPS; it += 2) {
      step(it,     w0h, w1h);
      step(it + 1, w1h, w0h);
    }

    float* dst = Db + (size_t)(kkp * 2 + kc) * T_NUM * H_DIM;
    #pragma unroll
    for (int mi = 0; mi < 4; ++mi) {
      #pragma unroll
      for (int jj = 0; jj < 4; ++jj) {
        int lm = wr * 64 + mi * 16 + fq * 4 + jj;
        int gm = m0 + lm;
        if (gm < cnt) {
          int tok = stok[gm];
          float p = sprb[gm];
          float* orow = dst + (size_t)tok * H_DIM + n0 + wc * 64 + fr;
          #pragma unroll
          for (int ni = 0; ni < 4; ++ni) orow[ni * 16] = p * acc[mi][ni][jj];
        }
      }
    }
  }
}

// fused SwiGLU + down-router; f16 inter out (r15-proven)
__global__ __launch_bounds__(256) void swiglu_router(const float* __restrict__ g,
    const float* __restrict__ u, const float* __restrict__ Rd,
    _Float16* __restrict__ gi, int* __restrict__ meta)
{
  int t = blockIdx.x, tid = threadIdx.x;
  float part[8];
  #pragma unroll
  for (int e = 0; e < 8; ++e) part[e] = 0.f;
  const float* gr = g + (size_t)t * I_DIM;
  const float* ur = u + (size_t)t * I_DIM;
  _Float16*    ir = gi + (size_t)t * I_DIM;
  #pragma unroll
  for (int cc = 0; cc < 4; ++cc) {
    int i = cc * 1024 + tid * 4;
    f32x4 gv = *(const f32x4*)(gr + i);
    f32x4 uv = *(const f32x4*)(ur + i);
    f32x4 iv;
    f16x4 hv;
    #pragma unroll
    for (int j = 0; j < 4; ++j) {
      float xx = gv[j];
      iv[j] = (xx / (1.f + expf(-xx))) * uv[j];
      hv[j] = (_Float16)iv[j];
    }
    *(f16x4*)(ir + i) = hv;
    #pragma unroll
    for (int e = 0; e < 8; ++e) {
      f32x4 rv = *(const f32x4*)(Rd + (size_t)e * I_DIM + i);
      part[e] += rv[0]*iv[0] + rv[1]*iv[1] + rv[2]*iv[2] + rv[3]*iv[3];
    }
  }
  __shared__ float red[4][8];
  int w = tid >> 6, lane = tid & 63;
  #pragma unroll
  for (int e = 0; e < 8; ++e) {
    float s = wave_sum(part[e]);
    if (lane == 0) red[w][e] = s;
  }
  __syncthreads();
  if (tid == 0) {
    float lg[8];
    #pragma unroll
    for (int e = 0; e < 8; ++e) lg[e] = red[0][e] + red[1][e] + red[2][e] + red[3][e];
    topk_write(meta, 2, t, lg);
  }
}

__global__ __launch_bounds__(256) void combine_kernel(float* __restrict__ out,
                                                      const float* __restrict__ scr)
{
  int i = blockIdx.x * 1024 + threadIdx.x * 4;
  f32x4 a = *(const f32x4*)(out + i);
  f32x4 b = *(const f32x4*)(scr + i);
  #pragma unroll
  for (int j = 0; j < 4; ++j) a[j] += b[j];
  *(f32x4*)(out + i) = a;
}

__global__ __launch_bounds__(256) void combine4_kernel(float* __restrict__ out,
                                                       const float* __restrict__ db)
{
  const size_t S = (size_t)T_NUM * H_DIM;
  int i = blockIdx.x * 1024 + threadIdx.x * 4;
  f32x4 a = *(const f32x4*)(db + i);
  f32x4 b = *(const f32x4*)(db + S + i);
  f32x4 c = *(const f32x4*)(db + 2 * S + i);
  f32x4 d = *(const f32x4*)(db + 3 * S + i);
  #pragma unroll
  for (int j = 0; j < 4; ++j) a[j] = (a[j] + b[j]) + (c[j] + d[j]);
  *(f32x4*)(out + i) = a;
}

extern "C" void kernel_launch(void* const* d_in, const int* in_sizes, int n_in,
                              void* d_out, int out_size, void* d_ws, size_t ws_size,
                              hipStream_t stream)
{
  const float* x  = (const float*)d_in[0];
  const float* Rg = (const float*)d_in[1];
  const float* Wg = (const float*)d_in[2];
  const float* Ru = (const float*)d_in[3];
  const float* Wu = (const float*)d_in[4];
  const float* Rd = (const float*)d_in[5];
  const float* Wd = (const float*)d_in[6];
  float* out = (float*)d_out;
  char* ws = (char*)d_ws;

  const size_t MB64 = 67108864;
  const size_t A_SZ = 20971520;

  if (ws_size >= (size_t)445644800) {
    // ---- big-ws path: de-aliased W planes + merged down (12 dispatches) ----
    _Float16* Wgh = (_Float16*)ws;
    _Float16* Wgl = (_Float16*)(ws + MB64);
    _Float16* Wuh = (_Float16*)(ws + 2 * MB64);
    _Float16* Wul = (_Float16*)(ws + 3 * MB64);
    float* g = (float*)(ws + 4 * MB64);
    float* u = (float*)(ws + 5 * MB64);
    int* meta = (int*)(ws + 6 * MB64);
    _Float16* A0 = (_Float16*)(ws + 6 * MB64 + 1048576);
    _Float16* A2 = (_Float16*)(ws + 6 * MB64 + 1048576 + A_SZ);
    _Float16* A1  = (_Float16*)u;      // dead until gemm(1,0) writes u
    _Float16* gi  = (_Float16*)Wgl;    // Wg planes dead after layer-0 gemms
    _Float16* Wdh = Wgh;               // Wd f16 image in dead Wgh
    _Float16* Ad0 = (_Float16*)u;      // u dead after swiglu
    _Float16* Ad1 = (_Float16*)g;      // g dead after swiglu
    float* db     = (float*)(ws + 2 * MB64);  // 4x[T,1024] f32 (67MB) in dead Wuh+Wul

    router_gu<<<dim3(T_NUM / 4), 256, 0, stream>>>(x, Rg, Ru, meta);
    route_finalize<<<dim3(1), 256, 0, stream>>>(meta, 0, 2);

    fused_cw3x2_ga<<<dim3(2 * CW3BLK + MAXTILES * 32), 256, 0, stream>>>(
        Wg, Wgh, Wgl, Wu, Wuh, Wul, x, A0, meta);
    moe_gemm9<3, 0, I_DIM, 32, 32, 1, 1><<<dim3(GEMMBLK), 256, 0, stream>>>(
        A0, Wgh, Wgl, g, g, meta, 0, 0, x, A1, 0, 1);
    moe_gemm9<3, 1, I_DIM, 32, 32, 1, 1><<<dim3(GEMMBLK), 256, 0, stream>>>(
        A1, Wgh, Wgl, g, g, meta, 0, 1, x, A0, 1, 0);
    moe_gemm9<3, 0, I_DIM, 32, 32, 1, 1><<<dim3(GEMMBLK), 256, 0, stream>>>(
        A0, Wuh, Wul, u, u, meta, 1, 0, x, A2, 1, 1);
    moe_gemm9<3, 1, I_DIM, 32, 32, 1, 0><<<dim3(GEMMBLK), 256, 0, stream>>>(
        A2, Wuh, Wul, u, u, meta, 1, 1, x, A2, 0, 0);

    swiglu_router<<<dim3(T_NUM), 256, 0, stream>>>(g, u, Rd, gi, meta);
    route_finalize<<<dim3(1), 256, 0, stream>>>(meta, 2, 1);

    // convert Wd + gather D(0)->Ad0 + gather D(1)->Ad1, one dispatch
    fused_cw1_gd<<<dim3(CW1BLK + 2 * GDBLK), 256, 0, stream>>>(Wd, Wdh, gi, Ad0, Ad1, meta);
    // merged down: both k-passes, 4 private buffers, no RMW
    moe_gemm_dn<<<dim3(GEMMBLK), 256, 0, stream>>>(Ad0, Ad1, Wdh, db, meta);
    combine4_kernel<<<dim3(T_NUM), 256, 0, stream>>>(out, db);
  } else {
    // ---- small-ws fallback: r21 sequence ----
    _Float16* Wth = (_Float16*)ws;
    _Float16* Wtl = (_Float16*)(ws + MB64);
    float* g   = (float*)(ws + (size_t)134217728);
    float* u   = (float*)(ws + (size_t)201326592);
    int*  meta = (int*)(ws + (size_t)268435456);
    _Float16* A0 = (_Float16*)(ws + (size_t)269484032);
    _Float16* A1 = (_Float16*)u;
    _Float16* gi = (_Float16*)Wtl;
    _Float16* Ad0 = (_Float16*)u;
    _Float16* Ad1 = (_Float16*)g;
    float* dscr = (float*)A0;

    router_gu<<<dim3(T_NUM / 4), 256, 0, stream>>>(x, Rg, Ru, meta);
    route_finalize<<<dim3(1), 256, 0, stream>>>(meta, 0, 2);

    fused_cw3_ga<<<dim3(CW3BLK + MAXTILES * 32), 256, 0, stream>>>(Wg, Wth, Wtl, x, A0, meta, 0, 0);
    moe_gemm9<3, 0, I_DIM, 32, 32, 1, 1><<<dim3(GEMMBLK), 256, 0, stream>>>(
        A0, Wth, Wtl, g, g, meta, 0, 0, x, A1, 0, 1);
    moe_gemm9<3, 1, I_DIM, 32, 32, 1, 1><<<dim3(GEMMBLK), 256, 0, stream>>>(
        A1, Wth, Wtl, g, g, meta, 0, 1, x, A0, 1, 0);
    fused_cw3_ga<<<dim3(CW3BLK), 256, 0, stream>>>(Wu, Wth, Wtl, x, A0, meta, 0, 0);
    moe_gemm9<3, 0, I_DIM, 32, 32, 1, 0><<<dim3(GEMMBLK), 256, 0, stream>>>(
        A0, Wth, Wtl, u, u, meta, 1, 0, x, A0, 0, 0);
    gather_a_k<<<dim3(MAXTILES * 32), 256, 0, stream>>>(x, A0, meta, 1, 1);
    moe_gemm9<3, 1, I_DIM, 32, 32, 1, 0><<<dim3(GEMMBLK), 256, 0, stream>>>(
        A0, Wth, Wtl, u, u, meta, 1, 1, x, A0, 0, 0);

    swiglu_router<<<dim3(T_NUM), 256, 0, stream>>>(g, u, Rd, gi, meta);
    route_finalize<<<dim3(1), 256, 0, stream>>>(meta, 2, 1);

    fused_cw1_gd<<<dim3(CW1BLK + GDBLK), 256, 0, stream>>>(Wd, Wth, gi, Ad0, Ad1, meta);
    moe_gemm9<1, 0, H_DIM, 8, 32, 2, 2><<<dim3(GEMMBLK), 256, 0, stream>>>(
        Ad0, Wth, Wth, out, dscr, meta, 2, 0, gi, Ad1, 0, 1);
    moe_gemm9<1, 1, H_DIM, 8, 32, 2, 0><<<dim3(GEMMBLK), 256, 0, stream>>>(
        Ad1, Wth, Wth, out, dscr, meta, 2, 1, gi, Ad1, 0, 1);
    combine_kernel<<<dim3(T_NUM), 256, 0, stream>>>(out, dscr);
  }
}